// Round 18
// baseline (417.495 us; speedup 1.0000x reference)
//
#include <hip/hip_runtime.h>

#define HD 128
#define CAPE 768
#define MAXR 16
#define NB_RS 128
#define RF_CH 16
#define KSTR 136   // K LDS row stride in u16
#define VSTR 72    // V tile row stride in u16

typedef unsigned short u16;
typedef unsigned long long u64;
typedef __attribute__((ext_vector_type(8))) short bf16x8;
typedef __attribute__((ext_vector_type(4))) float f32x4;
typedef __attribute__((ext_vector_type(4))) unsigned u32x4;

__device__ inline float b2f(unsigned u){ return __uint_as_float(u << 16); }
__device__ inline float b2fhi(unsigned u){ return __uint_as_float(u & 0xffff0000u); }
__device__ inline u16 f2b(float x){
  unsigned u = __float_as_uint(x);
  return (u16)((u + 0x7fffu + ((u >> 16) & 1u)) >> 16);
}

// ---------- reduction helpers ----------
__device__ inline float waveSum(float v){ for(int o=32;o;o>>=1) v += __shfl_down(v,o); return v; }
__device__ inline float waveMax(float v){ for(int o=32;o;o>>=1) v = fmaxf(v,__shfl_down(v,o)); return v; }

__device__ inline float blockSum128(float v, float* red){
  int j = threadIdx.x;
  float s = waveSum(v);
  __syncthreads();
  if ((j & 63) == 0) red[j >> 6] = s;
  __syncthreads();
  return red[0] + red[1];
}
__device__ inline float blockMax128(float v, float* red){
  int j = threadIdx.x;
  float s = waveMax(v);
  __syncthreads();
  if ((j & 63) == 0) red[j >> 6] = s;
  __syncthreads();
  return fmaxf(red[0], red[1]);
}

// ---------- region aggregation ----------
__global__ void k_count(const int* __restrict__ memb, int N, int* __restrict__ counts){
  __shared__ int h[64];
  int tid = threadIdx.x;
  if (tid < 64) h[tid] = 0;
  __syncthreads();
  for (int t = blockIdx.x*blockDim.x + tid; t < N; t += gridDim.x*blockDim.x)
    atomicAdd(&h[memb[t]], 1);
  __syncthreads();
  if (tid < 64){ int v = h[tid]; if (v) atomicAdd(&counts[tid], v); }
}

__global__ __launch_bounds__(128) void k_regsum_fast(const float* __restrict__ node,
                        const int* __restrict__ memb, int N, int R,
                        float* __restrict__ partials){
  int b = blockIdx.y, j = threadIdx.x, blk = blockIdx.x;
  int nb = gridDim.x;
  int per = (N + nb - 1) / nb;
  int t0 = blk * per;
  int t1 = t0 + per; if (t1 > N) t1 = N;
  float acc[MAXR];
  #pragma unroll
  for (int i = 0; i < MAXR; ++i) acc[i] = 0.f;
  const float* base = node + (long)b*N*HD + j;
  #pragma unroll 4
  for (int t = t0; t < t1; ++t){
    float v = base[(long)t*HD];
    int r = memb[t];
    #pragma unroll
    for (int i = 0; i < MAXR; ++i) acc[i] += (i == r) ? v : 0.f;
  }
  float* dst = partials + ((long)(b*nb + blk)*R)*HD + j;
  #pragma unroll
  for (int i = 0; i < MAXR; ++i)
    if (i < R) dst[(long)i*HD] = acc[i];
}

__global__ void k_regsum_lds(const float* __restrict__ node, const int* __restrict__ memb,
                             int N, int R, float* __restrict__ partials, int nb){
  extern __shared__ float acc[];
  int b = blockIdx.y, j = threadIdx.x;
  for (int r = 0; r < R; ++r) acc[r*HD + j] = 0.f;
  int per = (N + gridDim.x - 1) / gridDim.x;
  int t0 = blockIdx.x * per;
  int t1 = t0 + per; if (t1 > N) t1 = N;
  for (int t = t0; t < t1; ++t){
    int r = memb[t];
    acc[r*HD + j] += node[((long)b*N + t)*HD + j];
  }
  for (int r = 0; r < R; ++r)
    atomicAdd(&partials[((long)(b*nb)*R + r)*HD + j], acc[r*HD + j]);
}

// stage A: red2[c*total + i] = sum over blk chunk of partials[b][blk][r][j]
__global__ __launch_bounds__(128) void k_regfin1b(const float* __restrict__ partials,
                         int nb, int redN, int R, int total, float* __restrict__ red2){
  int c = blockIdx.y;
  int i = blockIdx.x*128 + threadIdx.x;
  if (i >= total) return;
  int j = i % HD;
  int r = (i / HD) % R;
  int b = i / (HD * R);
  int per = (redN + RF_CH - 1) / RF_CH;
  int k0 = c*per, k1 = k0 + per; if (k1 > redN) k1 = redN;
  float s = 0.f;
  for (int blk = k0; blk < k1; ++blk)
    s += partials[((long)(b*nb + blk)*R + r)*HD + j];
  red2[(long)c*total + i] = s;
}

// stage B: sum RF_CH chunks, divide by count, add region_init, write h_aug
__global__ void k_regfin2(const float* __restrict__ red2, int total,
                          const int* __restrict__ counts,
                          const float* __restrict__ rinit, float* __restrict__ h_aug,
                          int N, int R, int T, int B){
  int i = blockIdx.x*blockDim.x + threadIdx.x;
  if (i >= total) return;
  int j = i % HD; int r = (i/HD) % R; int b = i/(HD*R);
  float s = 0.f;
  #pragma unroll
  for (int c = 0; c < RF_CH; ++c)
    s += red2[(long)c*total + i];
  int cnt = counts[r];
  float v = (cnt > 0) ? s / (float)cnt : 0.f;
  v += rinit[r*HD + j];
  h_aug[((long)b*T + N + r)*HD + j] = v;
}

// copy node rows into h_aug AND compute raw = (h·v)*scale (fused)
__global__ __launch_bounds__(128) void k_copyraw(const float* __restrict__ node,
                      const float* __restrict__ v, float* __restrict__ h_aug,
                      float* __restrict__ raw, int N, int T, float scale){
  int t = blockIdx.x, b = blockIdx.y, j = threadIdx.x;
  __shared__ float red[2];
  long rowb = (long)b*T + t;
  float x;
  if (t < N){ x = node[((long)b*N + t)*HD + j]; h_aug[rowb*HD + j] = x; }
  else      { x = h_aug[rowb*HD + j]; }
  float s = blockSum128(x * v[j], red);
  if (j == 0) raw[rowb] = s * scale;
}

// ---------- incidence bitmask ----------
__global__ __launch_bounds__(256) void k_maskbuild(const float* __restrict__ Hinc, int E, int MW,
                        u64* __restrict__ maskw){
  int t = blockIdx.x;
  int wv = threadIdx.x >> 6, lane = threadIdx.x & 63;
  const float* hrow = Hinc + (long)t*E;
  for (int w = wv; w < MW; w += 4){
    int e = w*64 + lane;
    bool f = (e < E) && (hrow[e] != 0.f);
    u64 mk = __ballot(f);
    if (lane == 0) maskw[(long)t*MW + w] = mk;
  }
}

// ---------- cols from bitmask: ballot-compaction, deterministic, atomic-free ----------
__global__ __launch_bounds__(256) void k_colbuild2(const u64* __restrict__ maskw, int T, int MW,
                           u16* __restrict__ colidx, int* __restrict__ colcnt){
  int e = blockIdx.x;
  int w = e >> 6, bit = e & 63;
  int j = threadIdx.x;
  int lane = j & 63, wv = j >> 6;
  __shared__ int wsum[4];
  int c = 0;
  for (int base = 0; base < T; base += 256){
    int t = base + j;
    bool f = (t < T) && ((maskw[(long)t*MW + w] >> bit) & 1ull);
    u64 mk = __ballot(f);
    if (lane == 0) wsum[wv] = __popcll(mk);
    __syncthreads();
    int pre = 0;
    #pragma unroll
    for (int k = 0; k < 4; ++k) pre += (k < wv) ? wsum[k] : 0;
    int tot = wsum[0] + wsum[1] + wsum[2] + wsum[3];
    if (f){
      int pos = c + pre + (int)__popcll(mk & ((1ull << lane) - 1ull));
      if (pos < CAPE) colidx[(long)e*CAPE + pos] = (u16)t;
    }
    c += tot;
    __syncthreads();
  }
  if (j == 0) colcnt[e] = (c < CAPE) ? c : CAPE;
}

// ---------- small precomputes ----------
__global__ void k_ctxv(const float* __restrict__ ctx1, const float* __restrict__ W1h,
                       float* __restrict__ v){
  int l = blockIdx.x, k = threadIdx.x;
  float a = 0.f;
  for (int j = 0; j < HD; ++j) a += ctx1[l*HD + j] * W1h[((long)l*HD + j)*HD + k];
  v[l*HD + k] = a;
}

// MqTb[l][n][k] = bf16( sum_j W2h[l][j][n] * W3[l][j][k] )
__global__ void k_mm128(const float* __restrict__ W2h, const float* __restrict__ W3,
                        u16* __restrict__ MqTb){
  int n = blockIdx.x, l = blockIdx.y, k = threadIdx.x;
  const float* A = W2h + (long)l*HD*HD;
  const float* Bm = W3 + (long)l*HD*HD;
  float s = 0.f;
  for (int j = 0; j < HD; ++j) s += A[(long)j*HD + n] * Bm[(long)j*HD + k];
  MqTb[((long)l*HD + n)*HD + k] = f2b(s);
}

// convert W1, W2 to bf16 once
__global__ void k_wconv(const float* __restrict__ W1, const float* __restrict__ W2,
                        u16* __restrict__ W1b, u16* __restrict__ W2b, int total){
  int i = blockIdx.x*blockDim.x + threadIdx.x;
  if (i < total){
    W1b[i] = f2b(W1[i]);
    W2b[i] = f2b(W2[i]);
  }
}

// ---------- MFMA bf16 GEMM: C = A @ W^T, weights pre-converted bf16; blockIdx.y picks ----------
__global__ __launch_bounds__(256) void k_gemmM(const float* __restrict__ A,
                       const u16* __restrict__ Wa16, const u16* __restrict__ Wb16,
                       u16* __restrict__ Ca, u16* __restrict__ Cb, int M){
  const u16* W16 = blockIdx.y ? Wb16 : Wa16;
  u16* C = blockIdx.y ? Cb : Ca;
  __shared__ __align__(16) u16 Ws[128][KSTR];
  __shared__ __align__(16) u16 As[64][KSTR];
  int tid = threadIdx.x;
  int row0 = blockIdx.x * 64;
  for (int i = tid; i < 128*64; i += 256){
    int r = i >> 6, c2 = (i & 63) << 1;
    *(unsigned*)&Ws[r][c2] = *(const unsigned*)(W16 + (long)r*HD + c2);
  }
  for (int i = tid; i < 64*128; i += 256){
    int r = i >> 7, c = i & 127;
    int gr = row0 + r;
    As[r][c] = (gr < M) ? f2b(A[(long)gr*HD + c]) : (u16)0;
  }
  __syncthreads();

  int wave = tid >> 6, lane = tid & 63;
  int wr0 = wave * 16;
  int frow = lane & 15;
  int koff = (lane >> 4) * 8;
  f32x4 acc[8];
  #pragma unroll
  for (int f = 0; f < 8; ++f) acc[f] = (f32x4){0.f,0.f,0.f,0.f};

  #pragma unroll
  for (int ks = 0; ks < 4; ++ks){
    int kc = ks*32 + koff;
    bf16x8 av = *(const bf16x8*)&As[wr0 + frow][kc];
    #pragma unroll
    for (int f = 0; f < 8; ++f){
      bf16x8 bv = *(const bf16x8*)&Ws[f*16 + frow][kc];
      acc[f] = __builtin_amdgcn_mfma_f32_16x16x32_bf16(av, bv, acc[f], 0, 0, 0);
    }
  }

  int orow = wr0 + (lane >> 4) * 4;
  #pragma unroll
  for (int f = 0; f < 8; ++f){
    int col = f*16 + frow;
    #pragma unroll
    for (int i = 0; i < 4; ++i){
      int gr = row0 + orow + i;
      if (gr < M) C[(long)gr*HD + col] = f2b(acc[f][i]);
    }
  }
}

// ---------- hw2t[b][h][e] = sum_d W2[h][d] * hyper[b][e][d]  (bf16 out, e-major) ----------
__global__ __launch_bounds__(256) void k_gemmW2T(const u16* __restrict__ W2b,
                       const u16* __restrict__ hyb, u16* __restrict__ hw2t, int E){
  int b = blockIdx.y;
  int e0 = blockIdx.x * 64;
  __shared__ __align__(16) u16 As[128][KSTR];
  __shared__ __align__(16) u16 Bs[64][KSTR];
  int tid = threadIdx.x;
  for (int i = tid; i < 128*64; i += 256){
    int r = i >> 6, c2 = (i & 63) << 1;
    *(unsigned*)&As[r][c2] = *(const unsigned*)(W2b + (long)r*HD + c2);
  }
  {
    int er = tid >> 2, q = (tid & 3)*32;
    if (e0 + er < E){
      const uint4* src = (const uint4*)(hyb + ((long)b*E + e0 + er)*HD + q);
      uint4 w0 = src[0], w1 = src[1], w2 = src[2], w3 = src[3];
      *(uint4*)&Bs[er][q]    = w0;
      *(uint4*)&Bs[er][q+8]  = w1;
      *(uint4*)&Bs[er][q+16] = w2;
      *(uint4*)&Bs[er][q+24] = w3;
    } else {
      uint4 z = {0,0,0,0};
      *(uint4*)&Bs[er][q] = z; *(uint4*)&Bs[er][q+8] = z;
      *(uint4*)&Bs[er][q+16] = z; *(uint4*)&Bs[er][q+24] = z;
    }
  }
  __syncthreads();
  int wv = tid >> 6, lane = tid & 63;
  int lc = lane & 15, lg = lane >> 4;
  f32x4 acc[2][4];
  #pragma unroll
  for (int mt=0;mt<2;++mt)
    #pragma unroll
    for (int nf=0;nf<4;++nf) acc[mt][nf] = (f32x4){0.f,0.f,0.f,0.f};
  #pragma unroll
  for (int mt=0;mt<2;++mt){
    int hr = wv*32 + mt*16 + lc;
    #pragma unroll
    for (int ks=0;ks<4;++ks){
      bf16x8 av = *(const bf16x8*)&As[hr][ks*32 + lg*8];
      #pragma unroll
      for (int nf=0;nf<4;++nf){
        bf16x8 bv = *(const bf16x8*)&Bs[nf*16+lc][ks*32 + lg*8];
        acc[mt][nf] = __builtin_amdgcn_mfma_f32_16x16x32_bf16(av, bv, acc[mt][nf], 0,0,0);
      }
    }
  }
  #pragma unroll
  for (int mt=0;mt<2;++mt){
    #pragma unroll
    for (int nf=0;nf<4;++nf){
      #pragma unroll
      for (int i=0;i<4;++i){
        int h = wv*32 + mt*16 + lg*4 + i;
        int e = e0 + nf*16 + lc;
        if (e < E) hw2t[((long)b*HD + h)*E + e] = f2b(acc[mt][nf][i]);
      }
    }
  }
}

// ---------- stage 1: per-edge masked softmax + weighted sum of proj1 ----------
__global__ __launch_bounds__(128) void k_edge(int swz, const float* __restrict__ raw,
                      const u16* __restrict__ proj1b,
                      const int* __restrict__ colcnt, const u16* __restrict__ colidx,
                      u16* __restrict__ hyb, int T, int E){
  int bi = blockIdx.x;
  int b, e;
  if (swz){ int x = bi & 7; b = x >> 1; e = ((bi >> 3) << 1) | (x & 1); }
  else    { b = bi / E; e = bi - b*E; }
  int j = threadIdx.x;
  int lane = j & 63, w = j >> 6;
  __shared__ float red[2];
  __shared__ float wls[CAPE];
  __shared__ int   tls[CAPE];
  __shared__ float part[128];
  int c = colcnt[e]; if (c > CAPE) c = CAPE;
  const u16* ci = colidx + (long)e*CAPE;
  const float* rawb = raw + (long)b*T;
  unsigned* orow = (unsigned*)(hyb + ((long)b*E + e)*HD);
  if (c <= 0){ if (w == 0) orow[lane] = 0u; return; }
  float lm = -1e30f;
  for (int i = j; i < c; i += 128){
    int t = ci[i];
    float v = rawb[t];
    tls[i] = t;
    wls[i] = v;
    lm = fmaxf(lm, v);
  }
  float m = blockMax128(lm, red);
  float lz = 0.f;
  for (int i = j; i < c; i += 128){
    float x = __expf(wls[i] - m);
    wls[i] = x;
    lz += x;
  }
  float Z = blockSum128(lz, red);
  float invZ = 1.f / Z;
  const u16* pb = proj1b + (long)b*T*HD + 2*lane;
  float a00=0.f,a01=0.f,a10=0.f,a11=0.f;
  int i = w;
  for (; i + 2 < c; i += 4){
    int t0v = tls[i], t1v = tls[i+2];
    float w0 = wls[i], w1 = wls[i+2];
    unsigned u0 = *(const unsigned*)(pb + (long)t0v*HD);
    unsigned u1 = *(const unsigned*)(pb + (long)t1v*HD);
    a00 += w0 * b2f(u0 & 0xffffu);  a01 += w0 * b2fhi(u0);
    a10 += w1 * b2f(u1 & 0xffffu);  a11 += w1 * b2fhi(u1);
  }
  for (; i < c; i += 2){
    float w0 = wls[i];
    unsigned u0 = *(const unsigned*)(pb + (long)tls[i]*HD);
    a00 += w0 * b2f(u0 & 0xffffu);  a01 += w0 * b2fhi(u0);
  }
  float o0 = a00 + a10, o1 = a01 + a11;
  __syncthreads();
  if (w == 1){ part[lane*2] = o0; part[lane*2+1] = o1; }
  __syncthreads();
  if (w == 0){
    o0 = (o0 + part[lane*2])   * invZ;
    o1 = (o1 + part[lane*2+1]) * invZ;
    orow[lane] = (unsigned)f2b(o0) | ((unsigned)f2b(o1) << 16);
  }
}

// ---------- stage 2a: flash partial over an E-split (swapped-QK, exp2 domain) ----------
__global__ __launch_bounds__(256) void k_flashp(
      const u16* __restrict__ qtb, const u16* __restrict__ hyb, const u16* __restrict__ hw2t,
      const u64* __restrict__ maskw,
      u16* __restrict__ Opart, float* __restrict__ mpart, float* __restrict__ lpart,
      int T, int E, int half, float scale2){
  int b = blockIdx.y, Bc = gridDim.y;
  int s = blockIdx.z, nsplit = gridDim.z;
  int t0 = blockIdx.x * 64;
  int tid = threadIdx.x;
  int wv = tid >> 6, lane = tid & 63;
  int lc = lane & 15, lg = lane >> 4;

  __shared__ __align__(16) u16 Ks[64][KSTR];
  __shared__ __align__(16) u16 Vs[128][VSTR];

  int MW = (E + 63) >> 6;
  int ntile = (E + 63) / 64;
  int et0 = s * half;
  int etend = (s+1)*half < ntile ? (s+1)*half : ntile;
  if (s == nsplit-1) etend = ntile;

  int qrow = t0 + wv*16 + lc;
  bf16x8 qf[4];
  if (qrow < T){
    const u16* qr = qtb + ((long)b*T + qrow)*HD + lg*8;
    #pragma unroll
    for (int ks = 0; ks < 4; ++ks) qf[ks] = *(const bf16x8*)(qr + ks*32);
  } else {
    #pragma unroll
    for (int ks = 0; ks < 4; ++ks) qf[ks] = (bf16x8){0,0,0,0,0,0,0,0};
  }

  float m_s = -1e30f, l_s = 0.f;
  f32x4 Oa[8];
  #pragma unroll
  for (int f=0;f<8;++f) Oa[f] = (f32x4){0.f,0.f,0.f,0.f};

  const u16* hyB = hyb + (long)b*E*HD;
  const u16* vtB = hw2t + (long)b*HD*E;

  int kr = tid >> 2, kq = (tid & 3)*32;
  int vh = tid >> 1, vo = (tid & 1)*32;

  uint4 kreg0, kreg1, kreg2, kreg3, vreg0, vreg1, vreg2, vreg3;
  const uint4 zz = make_uint4(0u,0u,0u,0u);

  if (et0 < etend){
    int e0 = et0*64;
    if (e0 + kr < E){
      const uint4* sp = (const uint4*)(hyB + (long)(e0+kr)*HD + kq);
      kreg0=sp[0]; kreg1=sp[1]; kreg2=sp[2]; kreg3=sp[3];
    } else { kreg0=zz; kreg1=zz; kreg2=zz; kreg3=zz; }
    if (e0 + vo + 31 < E){
      const uint4* sp = (const uint4*)(vtB + (long)vh*E + e0 + vo);
      vreg0=sp[0]; vreg1=sp[1]; vreg2=sp[2]; vreg3=sp[3];
    } else {
      union { uint4 v[4]; u16 s[32]; } u;
      #pragma unroll
      for (int k=0;k<32;++k){ int e=e0+vo+k; u.s[k] = (e<E)? vtB[(long)vh*E+e] : (u16)0; }
      vreg0=u.v[0]; vreg1=u.v[1]; vreg2=u.v[2]; vreg3=u.v[3];
    }
  }

  for (int et = et0; et < etend; ++et){
    *(uint4*)&Ks[kr][kq]    = kreg0;
    *(uint4*)&Ks[kr][kq+8]  = kreg1;
    *(uint4*)&Ks[kr][kq+16] = kreg2;
    *(uint4*)&Ks[kr][kq+24] = kreg3;
    {
      int eb0 = vo;        int ne0 = eb0>>4; int ka0 = (ne0>>1)*32 + ((eb0>>2)&3)*8 + (ne0&1)*4;
      int eb1 = vo + 8;    int ne1 = eb1>>4; int ka1 = (ne1>>1)*32 + ((eb1>>2)&3)*8 + (ne1&1)*4;
      int eb2 = vo + 16;   int ne2 = eb2>>4; int ka2 = (ne2>>1)*32 + ((eb2>>2)&3)*8 + (ne2&1)*4;
      int eb3 = vo + 24;   int ne3 = eb3>>4; int ka3 = (ne3>>1)*32 + ((eb3>>2)&3)*8 + (ne3&1)*4;
      *(uint2*)&Vs[vh][ka0]   = make_uint2(vreg0.x, vreg0.y);
      *(uint2*)&Vs[vh][ka0+8] = make_uint2(vreg0.z, vreg0.w);
      *(uint2*)&Vs[vh][ka1]   = make_uint2(vreg1.x, vreg1.y);
      *(uint2*)&Vs[vh][ka1+8] = make_uint2(vreg1.z, vreg1.w);
      *(uint2*)&Vs[vh][ka2]   = make_uint2(vreg2.x, vreg2.y);
      *(uint2*)&Vs[vh][ka2+8] = make_uint2(vreg2.z, vreg2.w);
      *(uint2*)&Vs[vh][ka3]   = make_uint2(vreg3.x, vreg3.y);
      *(uint2*)&Vs[vh][ka3+8] = make_uint2(vreg3.z, vreg3.w);
    }
    __syncthreads();
    if (et + 1 < etend){
      int e0 = (et+1)*64;
      if (e0 + kr < E){
        const uint4* sp = (const uint4*)(hyB + (long)(e0+kr)*HD + kq);
        kreg0=sp[0]; kreg1=sp[1]; kreg2=sp[2]; kreg3=sp[3];
      } else { kreg0=zz; kreg1=zz; kreg2=zz; kreg3=zz; }
      if (e0 + vo + 31 < E){
        const uint4* sp = (const uint4*)(vtB + (long)vh*E + e0 + vo);
        vreg0=sp[0]; vreg1=sp[1]; vreg2=sp[2]; vreg3=sp[3];
      } else {
        union { uint4 v[4]; u16 s[32]; } u;
        #pragma unroll
        for (int k=0;k<32;++k){ int e=e0+vo+k; u.s[k] = (e<E)? vtB[(long)vh*E+e] : (u16)0; }
        vreg0=u.v[0]; vreg1=u.v[1]; vreg2=u.v[2]; vreg3=u.v[3];
      }
    }

    u64 mw = (qrow < T) ? maskw[(long)qrow*MW + et] : 0ull;

    f32x4 accS[4];
    #pragma unroll
    for (int ne=0;ne<4;++ne) accS[ne] = (f32x4){0.f,0.f,0.f,0.f};
    __builtin_amdgcn_s_setprio(1);
    #pragma unroll
    for (int ks=0;ks<4;++ks){
      #pragma unroll
      for (int ne=0;ne<4;++ne){
        bf16x8 kv = *(const bf16x8*)&Ks[ne*16+lc][ks*32 + lg*8];
        accS[ne] = __builtin_amdgcn_mfma_f32_16x16x32_bf16(kv, qf[ks], accS[ne], 0,0,0);
      }
    }
    __builtin_amdgcn_s_setprio(0);

    unsigned lo = (unsigned)mw, hi = (unsigned)(mw >> 32);
    unsigned nib[4];
    nib[0] = (lo >> (lg*4)) & 0xFu;
    nib[1] = (lo >> (16 + lg*4)) & 0xFu;
    nib[2] = (hi >> (lg*4)) & 0xFu;
    nib[3] = (hi >> (16 + lg*4)) & 0xFu;

    float p[4][4];
    float mx = -3e30f;
    #pragma unroll
    for (int ne=0;ne<4;++ne){
      #pragma unroll
      for (int r=0;r<4;++r){
        float sv = ((nib[ne] >> r) & 1u) ? accS[ne][r]*scale2 : -3e30f;
        p[ne][r] = sv;
        mx = fmaxf(mx, sv);
      }
    }
    mx = fmaxf(mx, __shfl_xor(mx, 16));
    mx = fmaxf(mx, __shfl_xor(mx, 32));

    float corr = 1.f;
    if (!__all(mx <= m_s + 11.5416f)){   // 8 * log2(e)
      float mn = fmaxf(m_s, mx);
      corr = exp2f(m_s - mn);
      m_s = mn;
      float corrO[4];
      #pragma unroll
      for (int i=0;i<4;++i) corrO[i] = __shfl(corr, lg*4 + i, 16);
      #pragma unroll
      for (int f=0;f<8;++f){
        #pragma unroll
        for (int i=0;i<4;++i) Oa[f][i] *= corrO[i];
      }
    }

    float ls = 0.f;
    #pragma unroll
    for (int ne=0;ne<4;++ne){
      #pragma unroll
      for (int r=0;r<4;++r){
        float pv = exp2f(p[ne][r] - m_s);   // masked -3e30 underflows to exact 0
        p[ne][r] = pv;
        ls += pv;
      }
    }
    ls += __shfl_xor(ls, 16);
    ls += __shfl_xor(ls, 32);
    l_s = l_s*corr + ls;

    unsigned pk00, pk01, pk10, pk11, pk20, pk21, pk30, pk31;
    asm("v_cvt_pk_bf16_f32 %0, %1, %2" : "=v"(pk00) : "v"(p[0][0]), "v"(p[0][1]));
    asm("v_cvt_pk_bf16_f32 %0, %1, %2" : "=v"(pk01) : "v"(p[0][2]), "v"(p[0][3]));
    asm("v_cvt_pk_bf16_f32 %0, %1, %2" : "=v"(pk10) : "v"(p[1][0]), "v"(p[1][1]));
    asm("v_cvt_pk_bf16_f32 %0, %1, %2" : "=v"(pk11) : "v"(p[1][2]), "v"(p[1][3]));
    asm("v_cvt_pk_bf16_f32 %0, %1, %2" : "=v"(pk20) : "v"(p[2][0]), "v"(p[2][1]));
    asm("v_cvt_pk_bf16_f32 %0, %1, %2" : "=v"(pk21) : "v"(p[2][2]), "v"(p[2][3]));
    asm("v_cvt_pk_bf16_f32 %0, %1, %2" : "=v"(pk30) : "v"(p[3][0]), "v"(p[3][1]));
    asm("v_cvt_pk_bf16_f32 %0, %1, %2" : "=v"(pk31) : "v"(p[3][2]), "v"(p[3][3]));

    __builtin_amdgcn_s_setprio(1);
    {
      u32x4 w0v = { pk00, pk01, pk10, pk11 };
      bf16x8 pa0 = __builtin_bit_cast(bf16x8, w0v);
      #pragma unroll
      for (int f=0;f<8;++f){
        bf16x8 vb = *(const bf16x8*)&Vs[f*16+lc][lg*8];
        Oa[f] = __builtin_amdgcn_mfma_f32_16x16x32_bf16(pa0, vb, Oa[f], 0,0,0);
      }
      u32x4 w1v = { pk20, pk21, pk30, pk31 };
      bf16x8 pa1 = __builtin_bit_cast(bf16x8, w1v);
      #pragma unroll
      for (int f=0;f<8;++f){
        bf16x8 vb = *(const bf16x8*)&Vs[f*16+lc][32 + lg*8];
        Oa[f] = __builtin_amdgcn_mfma_f32_16x16x32_bf16(pa1, vb, Oa[f], 0,0,0);
      }
    }
    __builtin_amdgcn_s_setprio(0);
    __syncthreads();
  }

  // write partials (m/l in exp2 domain)
  u16* Ob = Opart + (((long)s*Bc + b)*T)*HD;
  #pragma unroll
  for (int i=0;i<4;++i){
    int t = t0 + wv*16 + lg*4 + i;
    if (t >= T) continue;
    #pragma unroll
    for (int f=0;f<8;++f)
      Ob[(long)t*HD + f*16 + lc] = f2b(Oa[f][i]);
  }
  if (lg == 0 && qrow < T){
    long mlrow = ((long)s*Bc + b)*T + qrow;
    mpart[mlrow] = m_s;
    lpart[mlrow] = l_s;
  }
}

// ---------- stage 2b: merge nsplit partials (exp2 domain) + residual + LN (+ fused next raw) ----------
__global__ __launch_bounds__(128) void k_merge(
      const u16* __restrict__ Opart, const float* __restrict__ mpart, const float* __restrict__ lpart,
      int nsplit,
      const float* __restrict__ lng, const float* __restrict__ lnb,
      const float* __restrict__ vnext, float* __restrict__ rawnext, int writeRaw,
      float* __restrict__ h_aug, float* __restrict__ out,
      int T, int N, int writeOut, float scale){
  int t = blockIdx.x, b = blockIdx.y, j = threadIdx.x;
  int Bc = gridDim.y;
  __shared__ float red[2];
  float M = -1e30f;
  for (int s = 0; s < nsplit; ++s)
    M = fmaxf(M, mpart[((long)s*Bc + b)*T + t]);
  float l = 0.f, o = 0.f;
  for (int s = 0; s < nsplit; ++s){
    long rr = ((long)s*Bc + b)*T + t;
    float cs = exp2f(mpart[rr] - M);
    l += lpart[rr] * cs;
    o += b2f(Opart[rr*HD + j]) * cs;
  }
  float inv = (l > 0.f) ? 1.f/l : 0.f;
  o *= inv;
  long rowb = (long)b*T + t;
  float x = o + h_aug[rowb*HD + j];
  float mean = blockSum128(x, red) * (1.f/HD);
  float d = x - mean;
  float var = blockSum128(d*d, red) * (1.f/HD);
  float y = d * rsqrtf(var + 1e-5f) * lng[j] + lnb[j];
  if (writeOut){
    if (t < N) out[((long)b*N + t)*HD + j] = y;
  } else {
    h_aug[rowb*HD + j] = y;
  }
  if (writeRaw){
    float s = blockSum128(y * vnext[j], red);
    if (j == 0) rawnext[rowb] = s * scale;
  }
}

extern "C" void kernel_launch(void* const* d_in, const int* in_sizes, int n_in,
                              void* d_out, int out_size, void* d_ws, size_t ws_size,
                              hipStream_t stream) {
  const float* node_emb = (const float*)d_in[0];
  const float* Hinc     = (const float*)d_in[1];
  const int*   memb     = (const int*)d_in[2];
  const float* W1       = (const float*)d_in[3];
  const float* W1h      = (const float*)d_in[4];
  const float* ctx1     = (const float*)d_in[5];
  const float* W2       = (const float*)d_in[6];
  const float* W2h      = (const float*)d_in[7];
  const float* W3       = (const float*)d_in[8];
  const float* lng      = (const float*)d_in[9];
  const float* lnb      = (const float*)d_in[10];
  const float* rinit    = (const float*)d_in[11];
  float* out = (float*)d_out;

  const int N  = in_sizes[2];
  const int Hd = in_sizes[3] / in_sizes[5];
  const int L  = in_sizes[5] / Hd;
  const int R  = in_sizes[11] / Hd;
  const int B  = in_sizes[0] / (N * Hd);
  const int T  = N + R;
  const int E  = in_sizes[1] / T;
  const int MW = (E + 63) / 64;
  const float scale = 1.0f / sqrtf((float)Hd);
  const float scale2 = scale * 1.44269504089f;   // fold log2(e): softmax in exp2 domain

  char* p = (char*)d_ws;
  auto carve = [&](size_t bytes){ char* r = p; p += (bytes + 255) & ~(size_t)255; return (void*)r; };
  float* h_aug  = (float*)carve((size_t)B*T*Hd*4);
  u16*   proj1b = (u16*)  carve((size_t)B*T*Hd*2);
  u16*   qtb    = (u16*)  carve((size_t)B*T*Hd*2);
  u16*   hyb    = (u16*)  carve((size_t)B*E*Hd*2);
  u16*   hw2t   = (u16*)  carve((size_t)B*Hd*E*2);
  u16*   MqTb   = (u16*)  carve((size_t)L*Hd*Hd*2);
  u16*   W1b    = (u16*)  carve((size_t)L*Hd*Hd*2);
  u16*   W2b    = (u16*)  carve((size_t)L*Hd*Hd*2);
  float* rawb   = (float*)carve((size_t)B*T*4);
  float* vbuf   = (float*)carve((size_t)L*Hd*4);
  u64*   maskw  = (u64*)  carve((size_t)T*MW*8);
  int* counts   = (int*)carve((size_t)R*4);
  int* col_cnt  = (int*)carve((size_t)E*4);
  u16* col_idx  = (u16*)carve((size_t)E*CAPE*2);
  float* mpart  = (float*)carve((size_t)4*B*T*4);
  float* lpart  = (float*)carve((size_t)4*B*T*4);
  float* red2   = (float*)carve((size_t)RF_CH*B*MAXR*Hd*4);

  // scratch: partials (prologue) then Opart (per-layer) — time-disjoint
  size_t used = (size_t)(p - (char*)d_ws);
  size_t rem  = (ws_size > used) ? (ws_size - used) : 0;
  size_t needP  = (size_t)B*NB_RS*R*Hd*4;
  size_t needO2 = (size_t)2*B*T*Hd*2;
  size_t needO4 = (size_t)4*B*T*Hd*2;
  size_t need2 = needP > needO2 ? needP : needO2;
  size_t need4 = needP > needO4 ? needP : needO4;
  int SPLIT = (rem >= need4) ? 4 : ((rem >= need2) ? 2 : 1);
  float* partials = (float*)p;
  u16*   Opart    = (u16*)p;

  hipMemsetAsync(counts, 0, (size_t)R*4, stream);

  k_count<<<32, 256, 0, stream>>>(memb, N, counts);

  int total = B*R*Hd;
  int redN;
  if (R <= MAXR){
    k_regsum_fast<<<dim3(NB_RS, B), 128, 0, stream>>>(node_emb, memb, N, R, partials);
    redN = NB_RS;
  } else {
    hipMemsetAsync(partials, 0, (size_t)B*R*Hd*4, stream);
    k_regsum_lds<<<dim3(16, B), Hd, (size_t)R*Hd*4, stream>>>(node_emb, memb, N, R, partials, NB_RS);
    redN = 1;
  }
  k_regfin1b<<<dim3((total+127)/128, RF_CH), 128, 0, stream>>>(partials, NB_RS, redN, R, total, red2);
  k_regfin2<<<(total+255)/256, 256, 0, stream>>>(red2, total, counts, rinit, h_aug, N, R, T, B);

  k_maskbuild<<<T, 256, 0, stream>>>(Hinc, E, MW, maskw);
  k_colbuild2<<<E, 256, 0, stream>>>(maskw, T, MW, col_idx, col_cnt);

  k_ctxv<<<L, Hd, 0, stream>>>(ctx1, W1h, vbuf);
  k_mm128<<<dim3(Hd, L), Hd, 0, stream>>>(W2h, W3, MqTb);
  int wtot = L*Hd*Hd;
  k_wconv<<<(wtot+255)/256, 256, 0, stream>>>(W1, W2, W1b, W2b, wtot);
  k_copyraw<<<dim3(T, B), 128, 0, stream>>>(node_emb, vbuf, h_aug, rawb, N, T, scale);

  int MT = B*T;
  int gTm = (MT + 63)/64;
  int gTf = (T + 63)/64;
  int gEt = (E + 63)/64;
  int ntile = (E + 63)/64;
  int half = (ntile + SPLIT - 1)/SPLIT;
  int swzE = (B == 4 && (E & 1) == 0) ? 1 : 0;
  for (int l = 0; l < L; ++l){
    size_t wo = (size_t)l*Hd*Hd;
    k_gemmM<<<dim3(gTm, 2), 256, 0, stream>>>(h_aug, W1b + wo, MqTb + wo, proj1b, qtb, MT);
    k_edge<<<B*E, 128, 0, stream>>>(swzE, rawb, proj1b, col_cnt, col_idx, hyb, T, E);
    k_gemmW2T<<<dim3(gEt, B), 256, 0, stream>>>(W2b + wo, hyb, hw2t, E);
    k_flashp<<<dim3(gTf, B, SPLIT), 256, 0, stream>>>(qtb, hyb, hw2t, maskw,
                                    Opart, mpart, lpart, T, E, half, scale2);
    int writeRaw = (l < L-1) ? 1 : 0;
    const float* vnext = vbuf + (size_t)((l+1 < L) ? (l+1) : l)*Hd;
    k_merge<<<dim3(T, B), 128, 0, stream>>>(Opart, mpart, lpart, SPLIT,
                                    lng + wo/Hd, lnb + wo/Hd,
                                    vnext, rawb, writeRaw,
                                    h_aug, out, T, N, (l == L-1) ? 1 : 0, scale);
  }
}

// Round 19
// 391.234 us; speedup vs baseline: 1.0671x; 1.0671x over previous
//
#include <hip/hip_runtime.h>

#define HD 128
#define CAPE 768
#define MAXR 16
#define NB_RS 128
#define RF_CH 16
#define KSTR 136   // K LDS row stride in u16
#define VSTR 72    // V tile row stride in u16

typedef unsigned short u16;
typedef unsigned long long u64;
typedef __attribute__((ext_vector_type(8))) short bf16x8;
typedef __attribute__((ext_vector_type(4))) float f32x4;
typedef __attribute__((ext_vector_type(4))) unsigned u32x4;

__device__ inline float b2f(unsigned u){ return __uint_as_float(u << 16); }
__device__ inline float b2fhi(unsigned u){ return __uint_as_float(u & 0xffff0000u); }
__device__ inline u16 f2b(float x){
  unsigned u = __float_as_uint(x);
  return (u16)((u + 0x7fffu + ((u >> 16) & 1u)) >> 16);
}

// ---------- reduction helpers ----------
__device__ inline float waveSum(float v){ for(int o=32;o;o>>=1) v += __shfl_down(v,o); return v; }
__device__ inline float waveMax(float v){ for(int o=32;o;o>>=1) v = fmaxf(v,__shfl_down(v,o)); return v; }

__device__ inline float blockSum128(float v, float* red){
  int j = threadIdx.x;
  float s = waveSum(v);
  __syncthreads();
  if ((j & 63) == 0) red[j >> 6] = s;
  __syncthreads();
  return red[0] + red[1];
}
__device__ inline float blockMax128(float v, float* red){
  int j = threadIdx.x;
  float s = waveMax(v);
  __syncthreads();
  if ((j & 63) == 0) red[j >> 6] = s;
  __syncthreads();
  return fmaxf(red[0], red[1]);
}

// ---------- region aggregation ----------
__global__ void k_count(const int* __restrict__ memb, int N, int* __restrict__ counts){
  __shared__ int h[64];
  int tid = threadIdx.x;
  if (tid < 64) h[tid] = 0;
  __syncthreads();
  for (int t = blockIdx.x*blockDim.x + tid; t < N; t += gridDim.x*blockDim.x)
    atomicAdd(&h[memb[t]], 1);
  __syncthreads();
  if (tid < 64){ int v = h[tid]; if (v) atomicAdd(&counts[tid], v); }
}

__global__ __launch_bounds__(128) void k_regsum_fast(const float* __restrict__ node,
                        const int* __restrict__ memb, int N, int R,
                        float* __restrict__ partials){
  int b = blockIdx.y, j = threadIdx.x, blk = blockIdx.x;
  int nb = gridDim.x;
  int per = (N + nb - 1) / nb;
  int t0 = blk * per;
  int t1 = t0 + per; if (t1 > N) t1 = N;
  float acc[MAXR];
  #pragma unroll
  for (int i = 0; i < MAXR; ++i) acc[i] = 0.f;
  const float* base = node + (long)b*N*HD + j;
  #pragma unroll 4
  for (int t = t0; t < t1; ++t){
    float v = base[(long)t*HD];
    int r = memb[t];
    #pragma unroll
    for (int i = 0; i < MAXR; ++i) acc[i] += (i == r) ? v : 0.f;
  }
  float* dst = partials + ((long)(b*nb + blk)*R)*HD + j;
  #pragma unroll
  for (int i = 0; i < MAXR; ++i)
    if (i < R) dst[(long)i*HD] = acc[i];
}

__global__ void k_regsum_lds(const float* __restrict__ node, const int* __restrict__ memb,
                             int N, int R, float* __restrict__ partials, int nb){
  extern __shared__ float acc[];
  int b = blockIdx.y, j = threadIdx.x;
  for (int r = 0; r < R; ++r) acc[r*HD + j] = 0.f;
  int per = (N + gridDim.x - 1) / gridDim.x;
  int t0 = blockIdx.x * per;
  int t1 = t0 + per; if (t1 > N) t1 = N;
  for (int t = t0; t < t1; ++t){
    int r = memb[t];
    acc[r*HD + j] += node[((long)b*N + t)*HD + j];
  }
  for (int r = 0; r < R; ++r)
    atomicAdd(&partials[((long)(b*nb)*R + r)*HD + j], acc[r*HD + j]);
}

// stage A: red2[c*total + i] = sum over blk chunk of partials[b][blk][r][j]
__global__ __launch_bounds__(128) void k_regfin1b(const float* __restrict__ partials,
                         int nb, int redN, int R, int total, float* __restrict__ red2){
  int c = blockIdx.y;
  int i = blockIdx.x*128 + threadIdx.x;
  if (i >= total) return;
  int j = i % HD;
  int r = (i / HD) % R;
  int b = i / (HD * R);
  int per = (redN + RF_CH - 1) / RF_CH;
  int k0 = c*per, k1 = k0 + per; if (k1 > redN) k1 = redN;
  float s = 0.f;
  for (int blk = k0; blk < k1; ++blk)
    s += partials[((long)(b*nb + blk)*R + r)*HD + j];
  red2[(long)c*total + i] = s;
}

// stage B: sum RF_CH chunks, divide by count, add region_init, write h_aug
__global__ void k_regfin2(const float* __restrict__ red2, int total,
                          const int* __restrict__ counts,
                          const float* __restrict__ rinit, float* __restrict__ h_aug,
                          int N, int R, int T, int B){
  int i = blockIdx.x*blockDim.x + threadIdx.x;
  if (i >= total) return;
  int j = i % HD; int r = (i/HD) % R; int b = i/(HD*R);
  float s = 0.f;
  #pragma unroll
  for (int c = 0; c < RF_CH; ++c)
    s += red2[(long)c*total + i];
  int cnt = counts[r];
  float v = (cnt > 0) ? s / (float)cnt : 0.f;
  v += rinit[r*HD + j];
  h_aug[((long)b*T + N + r)*HD + j] = v;
}

// copy node rows into h_aug AND compute raw = (h·v)*scale (fused)
__global__ __launch_bounds__(128) void k_copyraw(const float* __restrict__ node,
                      const float* __restrict__ v, float* __restrict__ h_aug,
                      float* __restrict__ raw, int N, int T, float scale){
  int t = blockIdx.x, b = blockIdx.y, j = threadIdx.x;
  __shared__ float red[2];
  long rowb = (long)b*T + t;
  float x;
  if (t < N){ x = node[((long)b*N + t)*HD + j]; h_aug[rowb*HD + j] = x; }
  else      { x = h_aug[rowb*HD + j]; }
  float s = blockSum128(x * v[j], red);
  if (j == 0) raw[rowb] = s * scale;
}

// ---------- incidence bitmask ----------
__global__ __launch_bounds__(256) void k_maskbuild(const float* __restrict__ Hinc, int E, int MW,
                        u64* __restrict__ maskw){
  int t = blockIdx.x;
  int wv = threadIdx.x >> 6, lane = threadIdx.x & 63;
  const float* hrow = Hinc + (long)t*E;
  for (int w = wv; w < MW; w += 4){
    int e = w*64 + lane;
    bool f = (e < E) && (hrow[e] != 0.f);
    u64 mk = __ballot(f);
    if (lane == 0) maskw[(long)t*MW + w] = mk;
  }
}

// ---------- cols from bitmask: ballot-compaction, deterministic, atomic-free ----------
__global__ __launch_bounds__(256) void k_colbuild2(const u64* __restrict__ maskw, int T, int MW,
                           u16* __restrict__ colidx, int* __restrict__ colcnt){
  int e = blockIdx.x;
  int w = e >> 6, bit = e & 63;
  int j = threadIdx.x;
  int lane = j & 63, wv = j >> 6;
  __shared__ int wsum[4];
  int c = 0;
  for (int base = 0; base < T; base += 256){
    int t = base + j;
    bool f = (t < T) && ((maskw[(long)t*MW + w] >> bit) & 1ull);
    u64 mk = __ballot(f);
    if (lane == 0) wsum[wv] = __popcll(mk);
    __syncthreads();
    int pre = 0;
    #pragma unroll
    for (int k = 0; k < 4; ++k) pre += (k < wv) ? wsum[k] : 0;
    int tot = wsum[0] + wsum[1] + wsum[2] + wsum[3];
    if (f){
      int pos = c + pre + (int)__popcll(mk & ((1ull << lane) - 1ull));
      if (pos < CAPE) colidx[(long)e*CAPE + pos] = (u16)t;
    }
    c += tot;
    __syncthreads();
  }
  if (j == 0) colcnt[e] = (c < CAPE) ? c : CAPE;
}

// ---------- small precomputes ----------
__global__ void k_ctxv(const float* __restrict__ ctx1, const float* __restrict__ W1h,
                       float* __restrict__ v){
  int l = blockIdx.x, k = threadIdx.x;
  float a = 0.f;
  for (int j = 0; j < HD; ++j) a += ctx1[l*HD + j] * W1h[((long)l*HD + j)*HD + k];
  v[l*HD + k] = a;
}

// MqTb[l][n][k] = bf16( sum_j W2h[l][j][n] * W3[l][j][k] )
__global__ void k_mm128(const float* __restrict__ W2h, const float* __restrict__ W3,
                        u16* __restrict__ MqTb){
  int n = blockIdx.x, l = blockIdx.y, k = threadIdx.x;
  const float* A = W2h + (long)l*HD*HD;
  const float* Bm = W3 + (long)l*HD*HD;
  float s = 0.f;
  for (int j = 0; j < HD; ++j) s += A[(long)j*HD + n] * Bm[(long)j*HD + k];
  MqTb[((long)l*HD + n)*HD + k] = f2b(s);
}

// convert W1, W2 to bf16 once
__global__ void k_wconv(const float* __restrict__ W1, const float* __restrict__ W2,
                        u16* __restrict__ W1b, u16* __restrict__ W2b, int total){
  int i = blockIdx.x*blockDim.x + threadIdx.x;
  if (i < total){
    W1b[i] = f2b(W1[i]);
    W2b[i] = f2b(W2[i]);
  }
}

// ---------- MFMA bf16 GEMM: C = A @ W^T, weights pre-converted bf16; blockIdx.y picks ----------
__global__ __launch_bounds__(256) void k_gemmM(const float* __restrict__ A,
                       const u16* __restrict__ Wa16, const u16* __restrict__ Wb16,
                       u16* __restrict__ Ca, u16* __restrict__ Cb, int M){
  const u16* W16 = blockIdx.y ? Wb16 : Wa16;
  u16* C = blockIdx.y ? Cb : Ca;
  __shared__ __align__(16) u16 Ws[128][KSTR];
  __shared__ __align__(16) u16 As[64][KSTR];
  int tid = threadIdx.x;
  int row0 = blockIdx.x * 64;
  for (int i = tid; i < 128*64; i += 256){
    int r = i >> 6, c2 = (i & 63) << 1;
    *(unsigned*)&Ws[r][c2] = *(const unsigned*)(W16 + (long)r*HD + c2);
  }
  for (int i = tid; i < 64*128; i += 256){
    int r = i >> 7, c = i & 127;
    int gr = row0 + r;
    As[r][c] = (gr < M) ? f2b(A[(long)gr*HD + c]) : (u16)0;
  }
  __syncthreads();

  int wave = tid >> 6, lane = tid & 63;
  int wr0 = wave * 16;
  int frow = lane & 15;
  int koff = (lane >> 4) * 8;
  f32x4 acc[8];
  #pragma unroll
  for (int f = 0; f < 8; ++f) acc[f] = (f32x4){0.f,0.f,0.f,0.f};

  #pragma unroll
  for (int ks = 0; ks < 4; ++ks){
    int kc = ks*32 + koff;
    bf16x8 av = *(const bf16x8*)&As[wr0 + frow][kc];
    #pragma unroll
    for (int f = 0; f < 8; ++f){
      bf16x8 bv = *(const bf16x8*)&Ws[f*16 + frow][kc];
      acc[f] = __builtin_amdgcn_mfma_f32_16x16x32_bf16(av, bv, acc[f], 0, 0, 0);
    }
  }

  int orow = wr0 + (lane >> 4) * 4;
  #pragma unroll
  for (int f = 0; f < 8; ++f){
    int col = f*16 + frow;
    #pragma unroll
    for (int i = 0; i < 4; ++i){
      int gr = row0 + orow + i;
      if (gr < M) C[(long)gr*HD + col] = f2b(acc[f][i]);
    }
  }
}

// ---------- hw2t[b][h][e] = sum_d W2[h][d] * hyper[b][e][d]  (bf16 out, e-major) ----------
__global__ __launch_bounds__(256) void k_gemmW2T(const u16* __restrict__ W2b,
                       const u16* __restrict__ hyb, u16* __restrict__ hw2t, int E){
  int b = blockIdx.y;
  int e0 = blockIdx.x * 64;
  __shared__ __align__(16) u16 As[128][KSTR];
  __shared__ __align__(16) u16 Bs[64][KSTR];
  int tid = threadIdx.x;
  for (int i = tid; i < 128*64; i += 256){
    int r = i >> 6, c2 = (i & 63) << 1;
    *(unsigned*)&As[r][c2] = *(const unsigned*)(W2b + (long)r*HD + c2);
  }
  {
    int er = tid >> 2, q = (tid & 3)*32;
    if (e0 + er < E){
      const uint4* src = (const uint4*)(hyb + ((long)b*E + e0 + er)*HD + q);
      uint4 w0 = src[0], w1 = src[1], w2 = src[2], w3 = src[3];
      *(uint4*)&Bs[er][q]    = w0;
      *(uint4*)&Bs[er][q+8]  = w1;
      *(uint4*)&Bs[er][q+16] = w2;
      *(uint4*)&Bs[er][q+24] = w3;
    } else {
      uint4 z = {0,0,0,0};
      *(uint4*)&Bs[er][q] = z; *(uint4*)&Bs[er][q+8] = z;
      *(uint4*)&Bs[er][q+16] = z; *(uint4*)&Bs[er][q+24] = z;
    }
  }
  __syncthreads();
  int wv = tid >> 6, lane = tid & 63;
  int lc = lane & 15, lg = lane >> 4;
  f32x4 acc[2][4];
  #pragma unroll
  for (int mt=0;mt<2;++mt)
    #pragma unroll
    for (int nf=0;nf<4;++nf) acc[mt][nf] = (f32x4){0.f,0.f,0.f,0.f};
  #pragma unroll
  for (int mt=0;mt<2;++mt){
    int hr = wv*32 + mt*16 + lc;
    #pragma unroll
    for (int ks=0;ks<4;++ks){
      bf16x8 av = *(const bf16x8*)&As[hr][ks*32 + lg*8];
      #pragma unroll
      for (int nf=0;nf<4;++nf){
        bf16x8 bv = *(const bf16x8*)&Bs[nf*16+lc][ks*32 + lg*8];
        acc[mt][nf] = __builtin_amdgcn_mfma_f32_16x16x32_bf16(av, bv, acc[mt][nf], 0,0,0);
      }
    }
  }
  #pragma unroll
  for (int mt=0;mt<2;++mt){
    #pragma unroll
    for (int nf=0;nf<4;++nf){
      #pragma unroll
      for (int i=0;i<4;++i){
        int h = wv*32 + mt*16 + lg*4 + i;
        int e = e0 + nf*16 + lc;
        if (e < E) hw2t[((long)b*HD + h)*E + e] = f2b(acc[mt][nf][i]);
      }
    }
  }
}

// ---------- stage 1: per-edge masked softmax + weighted sum of proj1 ----------
__global__ __launch_bounds__(128) void k_edge(int swz, const float* __restrict__ raw,
                      const u16* __restrict__ proj1b,
                      const int* __restrict__ colcnt, const u16* __restrict__ colidx,
                      u16* __restrict__ hyb, int T, int E){
  int bi = blockIdx.x;
  int b, e;
  if (swz){ int x = bi & 7; b = x >> 1; e = ((bi >> 3) << 1) | (x & 1); }
  else    { b = bi / E; e = bi - b*E; }
  int j = threadIdx.x;
  int lane = j & 63, w = j >> 6;
  __shared__ float red[2];
  __shared__ float wls[CAPE];
  __shared__ int   tls[CAPE];
  __shared__ float part[128];
  int c = colcnt[e]; if (c > CAPE) c = CAPE;
  const u16* ci = colidx + (long)e*CAPE;
  const float* rawb = raw + (long)b*T;
  unsigned* orow = (unsigned*)(hyb + ((long)b*E + e)*HD);
  if (c <= 0){ if (w == 0) orow[lane] = 0u; return; }
  float lm = -1e30f;
  for (int i = j; i < c; i += 128){
    int t = ci[i];
    float v = rawb[t];
    tls[i] = t;
    wls[i] = v;
    lm = fmaxf(lm, v);
  }
  float m = blockMax128(lm, red);
  float lz = 0.f;
  for (int i = j; i < c; i += 128){
    float x = __expf(wls[i] - m);
    wls[i] = x;
    lz += x;
  }
  float Z = blockSum128(lz, red);
  float invZ = 1.f / Z;
  const u16* pb = proj1b + (long)b*T*HD + 2*lane;
  float a00=0.f,a01=0.f,a10=0.f,a11=0.f;
  int i = w;
  for (; i + 2 < c; i += 4){
    int t0v = tls[i], t1v = tls[i+2];
    float w0 = wls[i], w1 = wls[i+2];
    unsigned u0 = *(const unsigned*)(pb + (long)t0v*HD);
    unsigned u1 = *(const unsigned*)(pb + (long)t1v*HD);
    a00 += w0 * b2f(u0 & 0xffffu);  a01 += w0 * b2fhi(u0);
    a10 += w1 * b2f(u1 & 0xffffu);  a11 += w1 * b2fhi(u1);
  }
  for (; i < c; i += 2){
    float w0 = wls[i];
    unsigned u0 = *(const unsigned*)(pb + (long)tls[i]*HD);
    a00 += w0 * b2f(u0 & 0xffffu);  a01 += w0 * b2fhi(u0);
  }
  float o0 = a00 + a10, o1 = a01 + a11;
  __syncthreads();
  if (w == 1){ part[lane*2] = o0; part[lane*2+1] = o1; }
  __syncthreads();
  if (w == 0){
    o0 = (o0 + part[lane*2])   * invZ;
    o1 = (o1 + part[lane*2+1]) * invZ;
    orow[lane] = (unsigned)f2b(o0) | ((unsigned)f2b(o1) << 16);
  }
}

// ---------- stage 2a: flash partial over an E-split (swapped-QK, exp2 domain) ----------
__global__ __launch_bounds__(256) void k_flashp(
      const u16* __restrict__ qtb, const u16* __restrict__ hyb, const u16* __restrict__ hw2t,
      const u64* __restrict__ maskw,
      u16* __restrict__ Opart, float* __restrict__ mpart, float* __restrict__ lpart,
      int T, int E, int half, float scale2){
  int b = blockIdx.y, Bc = gridDim.y;
  int s = blockIdx.z, nsplit = gridDim.z;
  int t0 = blockIdx.x * 64;
  int tid = threadIdx.x;
  int wv = tid >> 6, lane = tid & 63;
  int lc = lane & 15, lg = lane >> 4;

  __shared__ __align__(16) u16 Ks[64][KSTR];
  __shared__ __align__(16) u16 Vs[128][VSTR];

  int MW = (E + 63) >> 6;
  int ntile = (E + 63) / 64;
  int et0 = s * half;
  int etend = (s+1)*half < ntile ? (s+1)*half : ntile;
  if (s == nsplit-1) etend = ntile;

  int qrow = t0 + wv*16 + lc;
  bf16x8 qf[4];
  if (qrow < T){
    const u16* qr = qtb + ((long)b*T + qrow)*HD + lg*8;
    #pragma unroll
    for (int ks = 0; ks < 4; ++ks) qf[ks] = *(const bf16x8*)(qr + ks*32);
  } else {
    #pragma unroll
    for (int ks = 0; ks < 4; ++ks) qf[ks] = (bf16x8){0,0,0,0,0,0,0,0};
  }

  float m_s = -1e30f, l_s = 0.f;
  f32x4 Oa[8];
  #pragma unroll
  for (int f=0;f<8;++f) Oa[f] = (f32x4){0.f,0.f,0.f,0.f};

  const u16* hyB = hyb + (long)b*E*HD;
  const u16* vtB = hw2t + (long)b*HD*E;

  int kr = tid >> 2, kq = (tid & 3)*32;
  int vh = tid >> 1, vo = (tid & 1)*32;

  uint4 kreg0, kreg1, kreg2, kreg3, vreg0, vreg1, vreg2, vreg3;
  const uint4 zz = make_uint4(0u,0u,0u,0u);

  if (et0 < etend){
    int e0 = et0*64;
    if (e0 + kr < E){
      const uint4* sp = (const uint4*)(hyB + (long)(e0+kr)*HD + kq);
      kreg0=sp[0]; kreg1=sp[1]; kreg2=sp[2]; kreg3=sp[3];
    } else { kreg0=zz; kreg1=zz; kreg2=zz; kreg3=zz; }
    if (e0 + vo + 31 < E){
      const uint4* sp = (const uint4*)(vtB + (long)vh*E + e0 + vo);
      vreg0=sp[0]; vreg1=sp[1]; vreg2=sp[2]; vreg3=sp[3];
    } else {
      union { uint4 v[4]; u16 s[32]; } u;
      #pragma unroll
      for (int k=0;k<32;++k){ int e=e0+vo+k; u.s[k] = (e<E)? vtB[(long)vh*E+e] : (u16)0; }
      vreg0=u.v[0]; vreg1=u.v[1]; vreg2=u.v[2]; vreg3=u.v[3];
    }
  }

  for (int et = et0; et < etend; ++et){
    *(uint4*)&Ks[kr][kq]    = kreg0;
    *(uint4*)&Ks[kr][kq+8]  = kreg1;
    *(uint4*)&Ks[kr][kq+16] = kreg2;
    *(uint4*)&Ks[kr][kq+24] = kreg3;
    {
      int eb0 = vo;        int ne0 = eb0>>4; int ka0 = (ne0>>1)*32 + ((eb0>>2)&3)*8 + (ne0&1)*4;
      int eb1 = vo + 8;    int ne1 = eb1>>4; int ka1 = (ne1>>1)*32 + ((eb1>>2)&3)*8 + (ne1&1)*4;
      int eb2 = vo + 16;   int ne2 = eb2>>4; int ka2 = (ne2>>1)*32 + ((eb2>>2)&3)*8 + (ne2&1)*4;
      int eb3 = vo + 24;   int ne3 = eb3>>4; int ka3 = (ne3>>1)*32 + ((eb3>>2)&3)*8 + (ne3&1)*4;
      *(uint2*)&Vs[vh][ka0]   = make_uint2(vreg0.x, vreg0.y);
      *(uint2*)&Vs[vh][ka0+8] = make_uint2(vreg0.z, vreg0.w);
      *(uint2*)&Vs[vh][ka1]   = make_uint2(vreg1.x, vreg1.y);
      *(uint2*)&Vs[vh][ka1+8] = make_uint2(vreg1.z, vreg1.w);
      *(uint2*)&Vs[vh][ka2]   = make_uint2(vreg2.x, vreg2.y);
      *(uint2*)&Vs[vh][ka2+8] = make_uint2(vreg2.z, vreg2.w);
      *(uint2*)&Vs[vh][ka3]   = make_uint2(vreg3.x, vreg3.y);
      *(uint2*)&Vs[vh][ka3+8] = make_uint2(vreg3.z, vreg3.w);
    }
    __syncthreads();
    if (et + 1 < etend){
      int e0 = (et+1)*64;
      if (e0 + kr < E){
        const uint4* sp = (const uint4*)(hyB + (long)(e0+kr)*HD + kq);
        kreg0=sp[0]; kreg1=sp[1]; kreg2=sp[2]; kreg3=sp[3];
      } else { kreg0=zz; kreg1=zz; kreg2=zz; kreg3=zz; }
      if (e0 + vo + 31 < E){
        const uint4* sp = (const uint4*)(vtB + (long)vh*E + e0 + vo);
        vreg0=sp[0]; vreg1=sp[1]; vreg2=sp[2]; vreg3=sp[3];
      } else {
        union { uint4 v[4]; u16 s[32]; } u;
        #pragma unroll
        for (int k=0;k<32;++k){ int e=e0+vo+k; u.s[k] = (e<E)? vtB[(long)vh*E+e] : (u16)0; }
        vreg0=u.v[0]; vreg1=u.v[1]; vreg2=u.v[2]; vreg3=u.v[3];
      }
    }

    u64 mw = (qrow < T) ? maskw[(long)qrow*MW + et] : 0ull;

    f32x4 accS[4];
    #pragma unroll
    for (int ne=0;ne<4;++ne) accS[ne] = (f32x4){0.f,0.f,0.f,0.f};
    __builtin_amdgcn_s_setprio(1);
    #pragma unroll
    for (int ks=0;ks<4;++ks){
      #pragma unroll
      for (int ne=0;ne<4;++ne){
        bf16x8 kv = *(const bf16x8*)&Ks[ne*16+lc][ks*32 + lg*8];
        accS[ne] = __builtin_amdgcn_mfma_f32_16x16x32_bf16(kv, qf[ks], accS[ne], 0,0,0);
      }
    }
    __builtin_amdgcn_s_setprio(0);

    unsigned lo = (unsigned)mw, hi = (unsigned)(mw >> 32);
    unsigned nib[4];
    nib[0] = (lo >> (lg*4)) & 0xFu;
    nib[1] = (lo >> (16 + lg*4)) & 0xFu;
    nib[2] = (hi >> (lg*4)) & 0xFu;
    nib[3] = (hi >> (16 + lg*4)) & 0xFu;

    float p[4][4];
    float mx = -3e30f;
    #pragma unroll
    for (int ne=0;ne<4;++ne){
      #pragma unroll
      for (int r=0;r<4;++r){
        float sv = ((nib[ne] >> r) & 1u) ? accS[ne][r]*scale2 : -3e30f;
        p[ne][r] = sv;
        mx = fmaxf(mx, sv);
      }
    }
    mx = fmaxf(mx, __shfl_xor(mx, 16));
    mx = fmaxf(mx, __shfl_xor(mx, 32));

    float corr = 1.f;
    if (!__all(mx <= m_s + 11.5416f)){   // 8 * log2(e)
      float mn = fmaxf(m_s, mx);
      corr = exp2f(m_s - mn);
      m_s = mn;
      float corrO[4];
      #pragma unroll
      for (int i=0;i<4;++i) corrO[i] = __shfl(corr, lg*4 + i, 16);
      #pragma unroll
      for (int f=0;f<8;++f){
        #pragma unroll
        for (int i=0;i<4;++i) Oa[f][i] *= corrO[i];
      }
    }

    float ls = 0.f;
    #pragma unroll
    for (int ne=0;ne<4;++ne){
      #pragma unroll
      for (int r=0;r<4;++r){
        float pv = exp2f(p[ne][r] - m_s);   // masked -3e30 underflows to exact 0
        p[ne][r] = pv;
        ls += pv;
      }
    }
    ls += __shfl_xor(ls, 16);
    ls += __shfl_xor(ls, 32);
    l_s = l_s*corr + ls;

    unsigned pk00, pk01, pk10, pk11, pk20, pk21, pk30, pk31;
    asm("v_cvt_pk_bf16_f32 %0, %1, %2" : "=v"(pk00) : "v"(p[0][0]), "v"(p[0][1]));
    asm("v_cvt_pk_bf16_f32 %0, %1, %2" : "=v"(pk01) : "v"(p[0][2]), "v"(p[0][3]));
    asm("v_cvt_pk_bf16_f32 %0, %1, %2" : "=v"(pk10) : "v"(p[1][0]), "v"(p[1][1]));
    asm("v_cvt_pk_bf16_f32 %0, %1, %2" : "=v"(pk11) : "v"(p[1][2]), "v"(p[1][3]));
    asm("v_cvt_pk_bf16_f32 %0, %1, %2" : "=v"(pk20) : "v"(p[2][0]), "v"(p[2][1]));
    asm("v_cvt_pk_bf16_f32 %0, %1, %2" : "=v"(pk21) : "v"(p[2][2]), "v"(p[2][3]));
    asm("v_cvt_pk_bf16_f32 %0, %1, %2" : "=v"(pk30) : "v"(p[3][0]), "v"(p[3][1]));
    asm("v_cvt_pk_bf16_f32 %0, %1, %2" : "=v"(pk31) : "v"(p[3][2]), "v"(p[3][3]));

    __builtin_amdgcn_s_setprio(1);
    {
      u32x4 w0v = { pk00, pk01, pk10, pk11 };
      bf16x8 pa0 = __builtin_bit_cast(bf16x8, w0v);
      #pragma unroll
      for (int f=0;f<8;++f){
        bf16x8 vb = *(const bf16x8*)&Vs[f*16+lc][lg*8];
        Oa[f] = __builtin_amdgcn_mfma_f32_16x16x32_bf16(pa0, vb, Oa[f], 0,0,0);
      }
      u32x4 w1v = { pk20, pk21, pk30, pk31 };
      bf16x8 pa1 = __builtin_bit_cast(bf16x8, w1v);
      #pragma unroll
      for (int f=0;f<8;++f){
        bf16x8 vb = *(const bf16x8*)&Vs[f*16+lc][32 + lg*8];
        Oa[f] = __builtin_amdgcn_mfma_f32_16x16x32_bf16(pa1, vb, Oa[f], 0,0,0);
      }
    }
    __builtin_amdgcn_s_setprio(0);
    __syncthreads();
  }

  // write partials (m/l in exp2 domain)
  u16* Ob = Opart + (((long)s*Bc + b)*T)*HD;
  #pragma unroll
  for (int i=0;i<4;++i){
    int t = t0 + wv*16 + lg*4 + i;
    if (t >= T) continue;
    #pragma unroll
    for (int f=0;f<8;++f)
      Ob[(long)t*HD + f*16 + lc] = f2b(Oa[f][i]);
  }
  if (lg == 0 && qrow < T){
    long mlrow = ((long)s*Bc + b)*T + qrow;
    mpart[mlrow] = m_s;
    lpart[mlrow] = l_s;
  }
}

// ---------- stage 2b: merge nsplit partials (exp2 domain) + residual + LN (+ fused next raw) ----------
__global__ __launch_bounds__(128) void k_merge(
      const u16* __restrict__ Opart, const float* __restrict__ mpart, const float* __restrict__ lpart,
      int nsplit,
      const float* __restrict__ lng, const float* __restrict__ lnb,
      const float* __restrict__ vnext, float* __restrict__ rawnext, int writeRaw,
      float* __restrict__ h_aug, float* __restrict__ out,
      int T, int N, int writeOut, float scale){
  int t = blockIdx.x, b = blockIdx.y, j = threadIdx.x;
  int Bc = gridDim.y;
  __shared__ float red[2];
  float M = -1e30f;
  for (int s = 0; s < nsplit; ++s)
    M = fmaxf(M, mpart[((long)s*Bc + b)*T + t]);
  float l = 0.f, o = 0.f;
  for (int s = 0; s < nsplit; ++s){
    long rr = ((long)s*Bc + b)*T + t;
    float cs = exp2f(mpart[rr] - M);
    l += lpart[rr] * cs;
    o += b2f(Opart[rr*HD + j]) * cs;
  }
  float inv = (l > 0.f) ? 1.f/l : 0.f;
  o *= inv;
  long rowb = (long)b*T + t;
  float x = o + h_aug[rowb*HD + j];
  float mean = blockSum128(x, red) * (1.f/HD);
  float d = x - mean;
  float var = blockSum128(d*d, red) * (1.f/HD);
  float y = d * rsqrtf(var + 1e-5f) * lng[j] + lnb[j];
  if (writeOut){
    if (t < N) out[((long)b*N + t)*HD + j] = y;
  } else {
    h_aug[rowb*HD + j] = y;
  }
  if (writeRaw){
    float s = blockSum128(y * vnext[j], red);
    if (j == 0) rawnext[rowb] = s * scale;
  }
}

extern "C" void kernel_launch(void* const* d_in, const int* in_sizes, int n_in,
                              void* d_out, int out_size, void* d_ws, size_t ws_size,
                              hipStream_t stream) {
  const float* node_emb = (const float*)d_in[0];
  const float* Hinc     = (const float*)d_in[1];
  const int*   memb     = (const int*)d_in[2];
  const float* W1       = (const float*)d_in[3];
  const float* W1h      = (const float*)d_in[4];
  const float* ctx1     = (const float*)d_in[5];
  const float* W2       = (const float*)d_in[6];
  const float* W2h      = (const float*)d_in[7];
  const float* W3       = (const float*)d_in[8];
  const float* lng      = (const float*)d_in[9];
  const float* lnb      = (const float*)d_in[10];
  const float* rinit    = (const float*)d_in[11];
  float* out = (float*)d_out;

  const int N  = in_sizes[2];
  const int Hd = in_sizes[3] / in_sizes[5];
  const int L  = in_sizes[5] / Hd;
  const int R  = in_sizes[11] / Hd;
  const int B  = in_sizes[0] / (N * Hd);
  const int T  = N + R;
  const int E  = in_sizes[1] / T;
  const int MW = (E + 63) / 64;
  const float scale = 1.0f / sqrtf((float)Hd);
  const float scale2 = scale * 1.44269504089f;   // fold log2(e): softmax in exp2 domain

  char* p = (char*)d_ws;
  auto carve = [&](size_t bytes){ char* r = p; p += (bytes + 255) & ~(size_t)255; return (void*)r; };
  float* h_aug  = (float*)carve((size_t)B*T*Hd*4);
  u16*   proj1b = (u16*)  carve((size_t)B*T*Hd*2);
  u16*   qtb    = (u16*)  carve((size_t)B*T*Hd*2);
  u16*   hyb    = (u16*)  carve((size_t)B*E*Hd*2);
  u16*   hw2t   = (u16*)  carve((size_t)B*Hd*E*2);
  u16*   MqTb   = (u16*)  carve((size_t)L*Hd*Hd*2);
  u16*   W1b    = (u16*)  carve((size_t)L*Hd*Hd*2);
  u16*   W2b    = (u16*)  carve((size_t)L*Hd*Hd*2);
  float* rawb   = (float*)carve((size_t)B*T*4);
  float* vbuf   = (float*)carve((size_t)L*Hd*4);
  u64*   maskw  = (u64*)  carve((size_t)T*MW*8);
  int* counts   = (int*)carve((size_t)R*4);
  int* col_cnt  = (int*)carve((size_t)E*4);
  u16* col_idx  = (u16*)carve((size_t)E*CAPE*2);
  float* mpart  = (float*)carve((size_t)2*B*T*4);
  float* lpart  = (float*)carve((size_t)2*B*T*4);
  float* red2   = (float*)carve((size_t)RF_CH*B*MAXR*Hd*4);

  // scratch: partials (prologue) then Opart (per-layer) — time-disjoint
  size_t used = (size_t)(p - (char*)d_ws);
  size_t rem  = (ws_size > used) ? (ws_size - used) : 0;
  size_t needP  = (size_t)B*NB_RS*R*Hd*4;
  size_t needO2 = (size_t)2*B*T*Hd*2;
  size_t need2 = needP > needO2 ? needP : needO2;
  int SPLIT = (rem >= need2) ? 2 : 1;
  float* partials = (float*)p;
  u16*   Opart    = (u16*)p;

  hipMemsetAsync(counts, 0, (size_t)R*4, stream);

  k_count<<<32, 256, 0, stream>>>(memb, N, counts);

  int total = B*R*Hd;
  int redN;
  if (R <= MAXR){
    k_regsum_fast<<<dim3(NB_RS, B), 128, 0, stream>>>(node_emb, memb, N, R, partials);
    redN = NB_RS;
  } else {
    hipMemsetAsync(partials, 0, (size_t)B*R*Hd*4, stream);
    k_regsum_lds<<<dim3(16, B), Hd, (size_t)R*Hd*4, stream>>>(node_emb, memb, N, R, partials, NB_RS);
    redN = 1;
  }
  k_regfin1b<<<dim3((total+127)/128, RF_CH), 128, 0, stream>>>(partials, NB_RS, redN, R, total, red2);
  k_regfin2<<<(total+255)/256, 256, 0, stream>>>(red2, total, counts, rinit, h_aug, N, R, T, B);

  k_maskbuild<<<T, 256, 0, stream>>>(Hinc, E, MW, maskw);
  k_colbuild2<<<E, 256, 0, stream>>>(maskw, T, MW, col_idx, col_cnt);

  k_ctxv<<<L, Hd, 0, stream>>>(ctx1, W1h, vbuf);
  k_mm128<<<dim3(Hd, L), Hd, 0, stream>>>(W2h, W3, MqTb);
  int wtot = L*Hd*Hd;
  k_wconv<<<(wtot+255)/256, 256, 0, stream>>>(W1, W2, W1b, W2b, wtot);
  k_copyraw<<<dim3(T, B), 128, 0, stream>>>(node_emb, vbuf, h_aug, rawb, N, T, scale);

  int MT = B*T;
  int gTm = (MT + 63)/64;
  int gTf = (T + 63)/64;
  int gEt = (E + 63)/64;
  int ntile = (E + 63)/64;
  int half = (ntile + SPLIT - 1)/SPLIT;
  int swzE = (B == 4 && (E & 1) == 0) ? 1 : 0;
  for (int l = 0; l < L; ++l){
    size_t wo = (size_t)l*Hd*Hd;
    k_gemmM<<<dim3(gTm, 2), 256, 0, stream>>>(h_aug, W1b + wo, MqTb + wo, proj1b, qtb, MT);
    k_edge<<<B*E, 128, 0, stream>>>(swzE, rawb, proj1b, col_cnt, col_idx, hyb, T, E);
    k_gemmW2T<<<dim3(gEt, B), 256, 0, stream>>>(W2b + wo, hyb, hw2t, E);
    k_flashp<<<dim3(gTf, B, SPLIT), 256, 0, stream>>>(qtb, hyb, hw2t, maskw,
                                    Opart, mpart, lpart, T, E, half, scale2);
    int writeRaw = (l < L-1) ? 1 : 0;
    const float* vnext = vbuf + (size_t)((l+1 < L) ? (l+1) : l)*Hd;
    k_merge<<<dim3(T, B), 128, 0, stream>>>(Opart, mpart, lpart, SPLIT,
                                    lng + wo/Hd, lnb + wo/Hd,
                                    vnext, rawb, writeRaw,
                                    h_aug, out, T, N, (l == L-1) ? 1 : 0, scale);
  }
}

// Round 20
// 380.056 us; speedup vs baseline: 1.0985x; 1.0294x over previous
//
#include <hip/hip_runtime.h>

#define HD 128
#define CAPE 768
#define MAXR 16
#define NB_RS 128
#define RF_CH 16
#define KSTR 136   // K LDS row stride in u16
#define VSTR 72    // V tile row stride in u16

typedef unsigned short u16;
typedef unsigned long long u64;
typedef __attribute__((ext_vector_type(8))) short bf16x8;
typedef __attribute__((ext_vector_type(4))) float f32x4;
typedef __attribute__((ext_vector_type(4))) unsigned u32x4;

__device__ inline float b2f(unsigned u){ return __uint_as_float(u << 16); }
__device__ inline float b2fhi(unsigned u){ return __uint_as_float(u & 0xffff0000u); }
__device__ inline u16 f2b(float x){
  unsigned u = __float_as_uint(x);
  return (u16)((u + 0x7fffu + ((u >> 16) & 1u)) >> 16);
}

// ---------- reduction helpers ----------
__device__ inline float waveSum(float v){ for(int o=32;o;o>>=1) v += __shfl_down(v,o); return v; }
__device__ inline float waveMax(float v){ for(int o=32;o;o>>=1) v = fmaxf(v,__shfl_down(v,o)); return v; }

__device__ inline float blockSum128(float v, float* red){
  int j = threadIdx.x;
  float s = waveSum(v);
  __syncthreads();
  if ((j & 63) == 0) red[j >> 6] = s;
  __syncthreads();
  return red[0] + red[1];
}
__device__ inline float blockMax128(float v, float* red){
  int j = threadIdx.x;
  float s = waveMax(v);
  __syncthreads();
  if ((j & 63) == 0) red[j >> 6] = s;
  __syncthreads();
  return fmaxf(red[0], red[1]);
}

// ---------- region aggregation ----------
__global__ void k_count(const int* __restrict__ memb, int N, int* __restrict__ counts){
  __shared__ int h[64];
  int tid = threadIdx.x;
  if (tid < 64) h[tid] = 0;
  __syncthreads();
  for (int t = blockIdx.x*blockDim.x + tid; t < N; t += gridDim.x*blockDim.x)
    atomicAdd(&h[memb[t]], 1);
  __syncthreads();
  if (tid < 64){ int v = h[tid]; if (v) atomicAdd(&counts[tid], v); }
}

__global__ __launch_bounds__(128) void k_regsum_fast(const float* __restrict__ node,
                        const int* __restrict__ memb, int N, int R,
                        float* __restrict__ partials){
  int b = blockIdx.y, j = threadIdx.x, blk = blockIdx.x;
  int nb = gridDim.x;
  int per = (N + nb - 1) / nb;
  int t0 = blk * per;
  int t1 = t0 + per; if (t1 > N) t1 = N;
  float acc[MAXR];
  #pragma unroll
  for (int i = 0; i < MAXR; ++i) acc[i] = 0.f;
  const float* base = node + (long)b*N*HD + j;
  #pragma unroll 4
  for (int t = t0; t < t1; ++t){
    float v = base[(long)t*HD];
    int r = memb[t];
    #pragma unroll
    for (int i = 0; i < MAXR; ++i) acc[i] += (i == r) ? v : 0.f;
  }
  float* dst = partials + ((long)(b*nb + blk)*R)*HD + j;
  #pragma unroll
  for (int i = 0; i < MAXR; ++i)
    if (i < R) dst[(long)i*HD] = acc[i];
}

__global__ void k_regsum_lds(const float* __restrict__ node, const int* __restrict__ memb,
                             int N, int R, float* __restrict__ partials, int nb){
  extern __shared__ float acc[];
  int b = blockIdx.y, j = threadIdx.x;
  for (int r = 0; r < R; ++r) acc[r*HD + j] = 0.f;
  int per = (N + gridDim.x - 1) / gridDim.x;
  int t0 = blockIdx.x * per;
  int t1 = t0 + per; if (t1 > N) t1 = N;
  for (int t = t0; t < t1; ++t){
    int r = memb[t];
    acc[r*HD + j] += node[((long)b*N + t)*HD + j];
  }
  for (int r = 0; r < R; ++r)
    atomicAdd(&partials[((long)(b*nb)*R + r)*HD + j], acc[r*HD + j]);
}

// stage A: red2[c*total + i] = sum over blk chunk of partials[b][blk][r][j]
__global__ __launch_bounds__(128) void k_regfin1b(const float* __restrict__ partials,
                         int nb, int redN, int R, int total, float* __restrict__ red2){
  int c = blockIdx.y;
  int i = blockIdx.x*128 + threadIdx.x;
  if (i >= total) return;
  int j = i % HD;
  int r = (i / HD) % R;
  int b = i / (HD * R);
  int per = (redN + RF_CH - 1) / RF_CH;
  int k0 = c*per, k1 = k0 + per; if (k1 > redN) k1 = redN;
  float s = 0.f;
  for (int blk = k0; blk < k1; ++blk)
    s += partials[((long)(b*nb + blk)*R + r)*HD + j];
  red2[(long)c*total + i] = s;
}

// stage B: sum RF_CH chunks, divide by count, add region_init, write h_aug
__global__ void k_regfin2(const float* __restrict__ red2, int total,
                          const int* __restrict__ counts,
                          const float* __restrict__ rinit, float* __restrict__ h_aug,
                          int N, int R, int T, int B){
  int i = blockIdx.x*blockDim.x + threadIdx.x;
  if (i >= total) return;
  int j = i % HD; int r = (i/HD) % R; int b = i/(HD*R);
  float s = 0.f;
  #pragma unroll
  for (int c = 0; c < RF_CH; ++c)
    s += red2[(long)c*total + i];
  int cnt = counts[r];
  float v = (cnt > 0) ? s / (float)cnt : 0.f;
  v += rinit[r*HD + j];
  h_aug[((long)b*T + N + r)*HD + j] = v;
}

// copy node rows into h_aug AND compute raw = (h·v)*scale (fused)
__global__ __launch_bounds__(128) void k_copyraw(const float* __restrict__ node,
                      const float* __restrict__ v, float* __restrict__ h_aug,
                      float* __restrict__ raw, int N, int T, float scale){
  int t = blockIdx.x, b = blockIdx.y, j = threadIdx.x;
  __shared__ float red[2];
  long rowb = (long)b*T + t;
  float x;
  if (t < N){ x = node[((long)b*N + t)*HD + j]; h_aug[rowb*HD + j] = x; }
  else      { x = h_aug[rowb*HD + j]; }
  float s = blockSum128(x * v[j], red);
  if (j == 0) raw[rowb] = s * scale;
}

// ---------- incidence bitmask ----------
__global__ __launch_bounds__(256) void k_maskbuild(const float* __restrict__ Hinc, int E, int MW,
                        u64* __restrict__ maskw){
  int t = blockIdx.x;
  int wv = threadIdx.x >> 6, lane = threadIdx.x & 63;
  const float* hrow = Hinc + (long)t*E;
  for (int w = wv; w < MW; w += 4){
    int e = w*64 + lane;
    bool f = (e < E) && (hrow[e] != 0.f);
    u64 mk = __ballot(f);
    if (lane == 0) maskw[(long)t*MW + w] = mk;
  }
}

// ---------- cols from bitmask: ballot-compaction, deterministic, atomic-free ----------
__global__ __launch_bounds__(256) void k_colbuild2(const u64* __restrict__ maskw, int T, int MW,
                           u16* __restrict__ colidx, int* __restrict__ colcnt){
  int e = blockIdx.x;
  int w = e >> 6, bit = e & 63;
  int j = threadIdx.x;
  int lane = j & 63, wv = j >> 6;
  __shared__ int wsum[4];
  int c = 0;
  for (int base = 0; base < T; base += 256){
    int t = base + j;
    bool f = (t < T) && ((maskw[(long)t*MW + w] >> bit) & 1ull);
    u64 mk = __ballot(f);
    if (lane == 0) wsum[wv] = __popcll(mk);
    __syncthreads();
    int pre = 0;
    #pragma unroll
    for (int k = 0; k < 4; ++k) pre += (k < wv) ? wsum[k] : 0;
    int tot = wsum[0] + wsum[1] + wsum[2] + wsum[3];
    if (f){
      int pos = c + pre + (int)__popcll(mk & ((1ull << lane) - 1ull));
      if (pos < CAPE) colidx[(long)e*CAPE + pos] = (u16)t;
    }
    c += tot;
    __syncthreads();
  }
  if (j == 0) colcnt[e] = (c < CAPE) ? c : CAPE;
}

// ---------- small precomputes ----------
__global__ void k_ctxv(const float* __restrict__ ctx1, const float* __restrict__ W1h,
                       float* __restrict__ v){
  int l = blockIdx.x, k = threadIdx.x;
  float a = 0.f;
  for (int j = 0; j < HD; ++j) a += ctx1[l*HD + j] * W1h[((long)l*HD + j)*HD + k];
  v[l*HD + k] = a;
}

// MqTb[l][n][k] = bf16( sum_j W2h[l][j][n] * W3[l][j][k] )
__global__ void k_mm128(const float* __restrict__ W2h, const float* __restrict__ W3,
                        u16* __restrict__ MqTb){
  int n = blockIdx.x, l = blockIdx.y, k = threadIdx.x;
  const float* A = W2h + (long)l*HD*HD;
  const float* Bm = W3 + (long)l*HD*HD;
  float s = 0.f;
  for (int j = 0; j < HD; ++j) s += A[(long)j*HD + n] * Bm[(long)j*HD + k];
  MqTb[((long)l*HD + n)*HD + k] = f2b(s);
}

// convert W1, W2 to bf16 once
__global__ void k_wconv(const float* __restrict__ W1, const float* __restrict__ W2,
                        u16* __restrict__ W1b, u16* __restrict__ W2b, int total){
  int i = blockIdx.x*blockDim.x + threadIdx.x;
  if (i < total){
    W1b[i] = f2b(W1[i]);
    W2b[i] = f2b(W2[i]);
  }
}

// ---------- MFMA bf16 GEMM: C = A @ W^T, weights pre-converted bf16; blockIdx.y picks ----------
__global__ __launch_bounds__(256) void k_gemmM(const float* __restrict__ A,
                       const u16* __restrict__ Wa16, const u16* __restrict__ Wb16,
                       u16* __restrict__ Ca, u16* __restrict__ Cb, int M){
  const u16* W16 = blockIdx.y ? Wb16 : Wa16;
  u16* C = blockIdx.y ? Cb : Ca;
  __shared__ __align__(16) u16 Ws[128][KSTR];
  __shared__ __align__(16) u16 As[64][KSTR];
  int tid = threadIdx.x;
  int row0 = blockIdx.x * 64;
  for (int i = tid; i < 128*64; i += 256){
    int r = i >> 6, c2 = (i & 63) << 1;
    *(unsigned*)&Ws[r][c2] = *(const unsigned*)(W16 + (long)r*HD + c2);
  }
  for (int i = tid; i < 64*128; i += 256){
    int r = i >> 7, c = i & 127;
    int gr = row0 + r;
    As[r][c] = (gr < M) ? f2b(A[(long)gr*HD + c]) : (u16)0;
  }
  __syncthreads();

  int wave = tid >> 6, lane = tid & 63;
  int wr0 = wave * 16;
  int frow = lane & 15;
  int koff = (lane >> 4) * 8;
  f32x4 acc[8];
  #pragma unroll
  for (int f = 0; f < 8; ++f) acc[f] = (f32x4){0.f,0.f,0.f,0.f};

  #pragma unroll
  for (int ks = 0; ks < 4; ++ks){
    int kc = ks*32 + koff;
    bf16x8 av = *(const bf16x8*)&As[wr0 + frow][kc];
    #pragma unroll
    for (int f = 0; f < 8; ++f){
      bf16x8 bv = *(const bf16x8*)&Ws[f*16 + frow][kc];
      acc[f] = __builtin_amdgcn_mfma_f32_16x16x32_bf16(av, bv, acc[f], 0, 0, 0);
    }
  }

  int orow = wr0 + (lane >> 4) * 4;
  #pragma unroll
  for (int f = 0; f < 8; ++f){
    int col = f*16 + frow;
    #pragma unroll
    for (int i = 0; i < 4; ++i){
      int gr = row0 + orow + i;
      if (gr < M) C[(long)gr*HD + col] = f2b(acc[f][i]);
    }
  }
}

// ---------- hw2t[b][h][e] = sum_d W2[h][d] * hyper[b][e][d]  (bf16 out, e-major) ----------
__global__ __launch_bounds__(256) void k_gemmW2T(const u16* __restrict__ W2b,
                       const u16* __restrict__ hyb, u16* __restrict__ hw2t, int E){
  int b = blockIdx.y;
  int e0 = blockIdx.x * 64;
  __shared__ __align__(16) u16 As[128][KSTR];
  __shared__ __align__(16) u16 Bs[64][KSTR];
  int tid = threadIdx.x;
  for (int i = tid; i < 128*64; i += 256){
    int r = i >> 6, c2 = (i & 63) << 1;
    *(unsigned*)&As[r][c2] = *(const unsigned*)(W2b + (long)r*HD + c2);
  }
  {
    int er = tid >> 2, q = (tid & 3)*32;
    if (e0 + er < E){
      const uint4* src = (const uint4*)(hyb + ((long)b*E + e0 + er)*HD + q);
      uint4 w0 = src[0], w1 = src[1], w2 = src[2], w3 = src[3];
      *(uint4*)&Bs[er][q]    = w0;
      *(uint4*)&Bs[er][q+8]  = w1;
      *(uint4*)&Bs[er][q+16] = w2;
      *(uint4*)&Bs[er][q+24] = w3;
    } else {
      uint4 z = {0,0,0,0};
      *(uint4*)&Bs[er][q] = z; *(uint4*)&Bs[er][q+8] = z;
      *(uint4*)&Bs[er][q+16] = z; *(uint4*)&Bs[er][q+24] = z;
    }
  }
  __syncthreads();
  int wv = tid >> 6, lane = tid & 63;
  int lc = lane & 15, lg = lane >> 4;
  f32x4 acc[2][4];
  #pragma unroll
  for (int mt=0;mt<2;++mt)
    #pragma unroll
    for (int nf=0;nf<4;++nf) acc[mt][nf] = (f32x4){0.f,0.f,0.f,0.f};
  #pragma unroll
  for (int mt=0;mt<2;++mt){
    int hr = wv*32 + mt*16 + lc;
    #pragma unroll
    for (int ks=0;ks<4;++ks){
      bf16x8 av = *(const bf16x8*)&As[hr][ks*32 + lg*8];
      #pragma unroll
      for (int nf=0;nf<4;++nf){
        bf16x8 bv = *(const bf16x8*)&Bs[nf*16+lc][ks*32 + lg*8];
        acc[mt][nf] = __builtin_amdgcn_mfma_f32_16x16x32_bf16(av, bv, acc[mt][nf], 0,0,0);
      }
    }
  }
  #pragma unroll
  for (int mt=0;mt<2;++mt){
    #pragma unroll
    for (int nf=0;nf<4;++nf){
      #pragma unroll
      for (int i=0;i<4;++i){
        int h = wv*32 + mt*16 + lg*4 + i;
        int e = e0 + nf*16 + lc;
        if (e < E) hw2t[((long)b*HD + h)*E + e] = f2b(acc[mt][nf][i]);
      }
    }
  }
}

// ---------- stage 1: per-edge masked softmax + weighted sum of proj1 ----------
__global__ __launch_bounds__(128) void k_edge(int swz, const float* __restrict__ raw,
                      const u16* __restrict__ proj1b,
                      const int* __restrict__ colcnt, const u16* __restrict__ colidx,
                      u16* __restrict__ hyb, int T, int E){
  int bi = blockIdx.x;
  int b, e;
  if (swz){ int x = bi & 7; b = x >> 1; e = ((bi >> 3) << 1) | (x & 1); }
  else    { b = bi / E; e = bi - b*E; }
  int j = threadIdx.x;
  int lane = j & 63, w = j >> 6;
  __shared__ float red[2];
  __shared__ float wls[CAPE];
  __shared__ int   tls[CAPE];
  __shared__ float part[128];
  int c = colcnt[e]; if (c > CAPE) c = CAPE;
  const u16* ci = colidx + (long)e*CAPE;
  const float* rawb = raw + (long)b*T;
  unsigned* orow = (unsigned*)(hyb + ((long)b*E + e)*HD);
  if (c <= 0){ if (w == 0) orow[lane] = 0u; return; }
  float lm = -1e30f;
  for (int i = j; i < c; i += 128){
    int t = ci[i];
    float v = rawb[t];
    tls[i] = t;
    wls[i] = v;
    lm = fmaxf(lm, v);
  }
  float m = blockMax128(lm, red);
  float lz = 0.f;
  for (int i = j; i < c; i += 128){
    float x = __expf(wls[i] - m);
    wls[i] = x;
    lz += x;
  }
  float Z = blockSum128(lz, red);
  float invZ = 1.f / Z;
  const u16* pb = proj1b + (long)b*T*HD + 2*lane;
  float a00=0.f,a01=0.f,a10=0.f,a11=0.f;
  int i = w;
  for (; i + 2 < c; i += 4){
    int t0v = tls[i], t1v = tls[i+2];
    float w0 = wls[i], w1 = wls[i+2];
    unsigned u0 = *(const unsigned*)(pb + (long)t0v*HD);
    unsigned u1 = *(const unsigned*)(pb + (long)t1v*HD);
    a00 += w0 * b2f(u0 & 0xffffu);  a01 += w0 * b2fhi(u0);
    a10 += w1 * b2f(u1 & 0xffffu);  a11 += w1 * b2fhi(u1);
  }
  for (; i < c; i += 2){
    float w0 = wls[i];
    unsigned u0 = *(const unsigned*)(pb + (long)tls[i]*HD);
    a00 += w0 * b2f(u0 & 0xffffu);  a01 += w0 * b2fhi(u0);
  }
  float o0 = a00 + a10, o1 = a01 + a11;
  __syncthreads();
  if (w == 1){ part[lane*2] = o0; part[lane*2+1] = o1; }
  __syncthreads();
  if (w == 0){
    o0 = (o0 + part[lane*2])   * invZ;
    o1 = (o1 + part[lane*2+1]) * invZ;
    orow[lane] = (unsigned)f2b(o0) | ((unsigned)f2b(o1) << 16);
  }
}

// ---------- stage 2a: flash partial over an E-split (swapped-QK layout, r15 shape) ----------
__global__ __launch_bounds__(256) void k_flashp(
      const u16* __restrict__ qtb, const u16* __restrict__ hyb, const u16* __restrict__ hw2t,
      const u64* __restrict__ maskw,
      u16* __restrict__ Opart, float* __restrict__ mpart, float* __restrict__ lpart,
      int T, int E, int half, float scale){
  int b = blockIdx.y, Bc = gridDim.y;
  int s = blockIdx.z, nsplit = gridDim.z;
  int t0 = blockIdx.x * 64;
  int tid = threadIdx.x;
  int wv = tid >> 6, lane = tid & 63;
  int lc = lane & 15, lg = lane >> 4;

  __shared__ __align__(16) u16 Ks[64][KSTR];
  __shared__ __align__(16) u16 Vs[128][VSTR];

  int MW = (E + 63) >> 6;
  int ntile = (E + 63) / 64;
  int et0 = s * half;
  int etend = (s+1)*half < ntile ? (s+1)*half : ntile;
  if (s == nsplit-1) etend = ntile;

  int qrow = t0 + wv*16 + lc;
  bf16x8 qf[4];
  if (qrow < T){
    const u16* qr = qtb + ((long)b*T + qrow)*HD + lg*8;
    #pragma unroll
    for (int ks = 0; ks < 4; ++ks) qf[ks] = *(const bf16x8*)(qr + ks*32);
  } else {
    #pragma unroll
    for (int ks = 0; ks < 4; ++ks) qf[ks] = (bf16x8){0,0,0,0,0,0,0,0};
  }

  float m_s = -1e30f, l_s = 0.f;
  f32x4 Oa[8];
  #pragma unroll
  for (int f=0;f<8;++f) Oa[f] = (f32x4){0.f,0.f,0.f,0.f};

  const u16* hyB = hyb + (long)b*E*HD;
  const u16* vtB = hw2t + (long)b*HD*E;

  int kr = tid >> 2, kq = (tid & 3)*32;
  int vh = tid >> 1, vo = (tid & 1)*32;

  uint4 kreg0, kreg1, kreg2, kreg3, vreg0, vreg1, vreg2, vreg3;
  const uint4 zz = make_uint4(0u,0u,0u,0u);

  if (et0 < etend){
    int e0 = et0*64;
    if (e0 + kr < E){
      const uint4* sp = (const uint4*)(hyB + (long)(e0+kr)*HD + kq);
      kreg0=sp[0]; kreg1=sp[1]; kreg2=sp[2]; kreg3=sp[3];
    } else { kreg0=zz; kreg1=zz; kreg2=zz; kreg3=zz; }
    if (e0 + vo + 31 < E){
      const uint4* sp = (const uint4*)(vtB + (long)vh*E + e0 + vo);
      vreg0=sp[0]; vreg1=sp[1]; vreg2=sp[2]; vreg3=sp[3];
    } else {
      union { uint4 v[4]; u16 s[32]; } u;
      #pragma unroll
      for (int k=0;k<32;++k){ int e=e0+vo+k; u.s[k] = (e<E)? vtB[(long)vh*E+e] : (u16)0; }
      vreg0=u.v[0]; vreg1=u.v[1]; vreg2=u.v[2]; vreg3=u.v[3];
    }
  }

  for (int et = et0; et < etend; ++et){
    *(uint4*)&Ks[kr][kq]    = kreg0;
    *(uint4*)&Ks[kr][kq+8]  = kreg1;
    *(uint4*)&Ks[kr][kq+16] = kreg2;
    *(uint4*)&Ks[kr][kq+24] = kreg3;
    {
      int eb0 = vo;        int ne0 = eb0>>4; int ka0 = (ne0>>1)*32 + ((eb0>>2)&3)*8 + (ne0&1)*4;
      int eb1 = vo + 8;    int ne1 = eb1>>4; int ka1 = (ne1>>1)*32 + ((eb1>>2)&3)*8 + (ne1&1)*4;
      int eb2 = vo + 16;   int ne2 = eb2>>4; int ka2 = (ne2>>1)*32 + ((eb2>>2)&3)*8 + (ne2&1)*4;
      int eb3 = vo + 24;   int ne3 = eb3>>4; int ka3 = (ne3>>1)*32 + ((eb3>>2)&3)*8 + (ne3&1)*4;
      *(uint2*)&Vs[vh][ka0]   = make_uint2(vreg0.x, vreg0.y);
      *(uint2*)&Vs[vh][ka0+8] = make_uint2(vreg0.z, vreg0.w);
      *(uint2*)&Vs[vh][ka1]   = make_uint2(vreg1.x, vreg1.y);
      *(uint2*)&Vs[vh][ka1+8] = make_uint2(vreg1.z, vreg1.w);
      *(uint2*)&Vs[vh][ka2]   = make_uint2(vreg2.x, vreg2.y);
      *(uint2*)&Vs[vh][ka2+8] = make_uint2(vreg2.z, vreg2.w);
      *(uint2*)&Vs[vh][ka3]   = make_uint2(vreg3.x, vreg3.y);
      *(uint2*)&Vs[vh][ka3+8] = make_uint2(vreg3.z, vreg3.w);
    }
    __syncthreads();
    if (et + 1 < etend){
      int e0 = (et+1)*64;
      if (e0 + kr < E){
        const uint4* sp = (const uint4*)(hyB + (long)(e0+kr)*HD + kq);
        kreg0=sp[0]; kreg1=sp[1]; kreg2=sp[2]; kreg3=sp[3];
      } else { kreg0=zz; kreg1=zz; kreg2=zz; kreg3=zz; }
      if (e0 + vo + 31 < E){
        const uint4* sp = (const uint4*)(vtB + (long)vh*E + e0 + vo);
        vreg0=sp[0]; vreg1=sp[1]; vreg2=sp[2]; vreg3=sp[3];
      } else {
        union { uint4 v[4]; u16 s[32]; } u;
        #pragma unroll
        for (int k=0;k<32;++k){ int e=e0+vo+k; u.s[k] = (e<E)? vtB[(long)vh*E+e] : (u16)0; }
        vreg0=u.v[0]; vreg1=u.v[1]; vreg2=u.v[2]; vreg3=u.v[3];
      }
    }

    u64 mw = (qrow < T) ? maskw[(long)qrow*MW + et] : 0ull;

    f32x4 accS[4];
    #pragma unroll
    for (int ne=0;ne<4;++ne) accS[ne] = (f32x4){0.f,0.f,0.f,0.f};
    __builtin_amdgcn_s_setprio(1);
    #pragma unroll
    for (int ks=0;ks<4;++ks){
      #pragma unroll
      for (int ne=0;ne<4;++ne){
        bf16x8 kv = *(const bf16x8*)&Ks[ne*16+lc][ks*32 + lg*8];
        accS[ne] = __builtin_amdgcn_mfma_f32_16x16x32_bf16(kv, qf[ks], accS[ne], 0,0,0);
      }
    }
    __builtin_amdgcn_s_setprio(0);

    unsigned lo = (unsigned)mw, hi = (unsigned)(mw >> 32);
    unsigned nib[4];
    nib[0] = (lo >> (lg*4)) & 0xFu;
    nib[1] = (lo >> (16 + lg*4)) & 0xFu;
    nib[2] = (hi >> (lg*4)) & 0xFu;
    nib[3] = (hi >> (16 + lg*4)) & 0xFu;

    float p[4][4];
    float mx = -3e30f;
    #pragma unroll
    for (int ne=0;ne<4;++ne){
      #pragma unroll
      for (int r=0;r<4;++r){
        float sv = ((nib[ne] >> r) & 1u) ? accS[ne][r]*scale : -3e30f;
        p[ne][r] = sv;
        mx = fmaxf(mx, sv);
      }
    }
    mx = fmaxf(mx, __shfl_xor(mx, 16));
    mx = fmaxf(mx, __shfl_xor(mx, 32));

    float corr = 1.f;
    if (!__all(mx <= m_s + 8.f)){
      float mn = fmaxf(m_s, mx);
      corr = __expf(m_s - mn);
      m_s = mn;
      float corrO[4];
      #pragma unroll
      for (int i=0;i<4;++i) corrO[i] = __shfl(corr, lg*4 + i, 16);
      #pragma unroll
      for (int f=0;f<8;++f){
        #pragma unroll
        for (int i=0;i<4;++i) Oa[f][i] *= corrO[i];
      }
    }

    float ls = 0.f;
    #pragma unroll
    for (int ne=0;ne<4;++ne){
      #pragma unroll
      for (int r=0;r<4;++r){
        float pv = __expf(p[ne][r] - m_s);   // masked -3e30 underflows to exact 0
        p[ne][r] = pv;
        ls += pv;
      }
    }
    ls += __shfl_xor(ls, 16);
    ls += __shfl_xor(ls, 32);
    l_s = l_s*corr + ls;

    unsigned pk00, pk01, pk10, pk11, pk20, pk21, pk30, pk31;
    asm("v_cvt_pk_bf16_f32 %0, %1, %2" : "=v"(pk00) : "v"(p[0][0]), "v"(p[0][1]));
    asm("v_cvt_pk_bf16_f32 %0, %1, %2" : "=v"(pk01) : "v"(p[0][2]), "v"(p[0][3]));
    asm("v_cvt_pk_bf16_f32 %0, %1, %2" : "=v"(pk10) : "v"(p[1][0]), "v"(p[1][1]));
    asm("v_cvt_pk_bf16_f32 %0, %1, %2" : "=v"(pk11) : "v"(p[1][2]), "v"(p[1][3]));
    asm("v_cvt_pk_bf16_f32 %0, %1, %2" : "=v"(pk20) : "v"(p[2][0]), "v"(p[2][1]));
    asm("v_cvt_pk_bf16_f32 %0, %1, %2" : "=v"(pk21) : "v"(p[2][2]), "v"(p[2][3]));
    asm("v_cvt_pk_bf16_f32 %0, %1, %2" : "=v"(pk30) : "v"(p[3][0]), "v"(p[3][1]));
    asm("v_cvt_pk_bf16_f32 %0, %1, %2" : "=v"(pk31) : "v"(p[3][2]), "v"(p[3][3]));

    __builtin_amdgcn_s_setprio(1);
    {
      u32x4 w0v = { pk00, pk01, pk10, pk11 };
      bf16x8 pa0 = __builtin_bit_cast(bf16x8, w0v);
      #pragma unroll
      for (int f=0;f<8;++f){
        bf16x8 vb = *(const bf16x8*)&Vs[f*16+lc][lg*8];
        Oa[f] = __builtin_amdgcn_mfma_f32_16x16x32_bf16(pa0, vb, Oa[f], 0,0,0);
      }
      u32x4 w1v = { pk20, pk21, pk30, pk31 };
      bf16x8 pa1 = __builtin_bit_cast(bf16x8, w1v);
      #pragma unroll
      for (int f=0;f<8;++f){
        bf16x8 vb = *(const bf16x8*)&Vs[f*16+lc][32 + lg*8];
        Oa[f] = __builtin_amdgcn_mfma_f32_16x16x32_bf16(pa1, vb, Oa[f], 0,0,0);
      }
    }
    __builtin_amdgcn_s_setprio(0);
    __syncthreads();
  }

  // write partials
  u16* Ob = Opart + (((long)s*Bc + b)*T)*HD;
  #pragma unroll
  for (int i=0;i<4;++i){
    int t = t0 + wv*16 + lg*4 + i;
    if (t >= T) continue;
    #pragma unroll
    for (int f=0;f<8;++f)
      Ob[(long)t*HD + f*16 + lc] = f2b(Oa[f][i]);
  }
  if (lg == 0 && qrow < T){
    long mlrow = ((long)s*Bc + b)*T + qrow;
    mpart[mlrow] = m_s;
    lpart[mlrow] = l_s;
  }
}

// ---------- stage 2b: merge splits + residual + LN (+ fused next raw) ----------
__global__ __launch_bounds__(128) void k_merge(
      const u16* __restrict__ Opart, const float* __restrict__ mpart, const float* __restrict__ lpart,
      int nsplit,
      const float* __restrict__ lng, const float* __restrict__ lnb,
      const float* __restrict__ vnext, float* __restrict__ rawnext, int writeRaw,
      float* __restrict__ h_aug, float* __restrict__ out,
      int T, int N, int writeOut, float scale){
  int t = blockIdx.x, b = blockIdx.y, j = threadIdx.x;
  int Bc = gridDim.y;
  __shared__ float red[2];
  long r0 = ((long)b)*T + t;
  long r1 = ((long)Bc + b)*T + t;
  float m0 = mpart[r0], l0 = lpart[r0];
  float m1 = (nsplit > 1) ? mpart[r1] : -1e30f;
  float l1 = (nsplit > 1) ? lpart[r1] : 0.f;
  float M = fmaxf(m0, m1);
  float c0 = __expf(m0 - M), c1 = __expf(m1 - M);
  float l = l0*c0 + l1*c1;
  float inv = (l > 0.f) ? 1.f/l : 0.f;
  float o = b2f(Opart[r0*HD + j]) * c0;
  if (nsplit > 1) o += b2f(Opart[r1*HD + j]) * c1;
  o *= inv;
  long rowb = (long)b*T + t;
  float x = o + h_aug[rowb*HD + j];
  float mean = blockSum128(x, red) * (1.f/HD);
  float d = x - mean;
  float var = blockSum128(d*d, red) * (1.f/HD);
  float y = d * rsqrtf(var + 1e-5f) * lng[j] + lnb[j];
  if (writeOut){
    if (t < N) out[((long)b*N + t)*HD + j] = y;
  } else {
    h_aug[rowb*HD + j] = y;
  }
  if (writeRaw){
    float s = blockSum128(y * vnext[j], red);
    if (j == 0) rawnext[rowb] = s * scale;
  }
}

extern "C" void kernel_launch(void* const* d_in, const int* in_sizes, int n_in,
                              void* d_out, int out_size, void* d_ws, size_t ws_size,
                              hipStream_t stream) {
  const float* node_emb = (const float*)d_in[0];
  const float* Hinc     = (const float*)d_in[1];
  const int*   memb     = (const int*)d_in[2];
  const float* W1       = (const float*)d_in[3];
  const float* W1h      = (const float*)d_in[4];
  const float* ctx1     = (const float*)d_in[5];
  const float* W2       = (const float*)d_in[6];
  const float* W2h      = (const float*)d_in[7];
  const float* W3       = (const float*)d_in[8];
  const float* lng      = (const float*)d_in[9];
  const float* lnb      = (const float*)d_in[10];
  const float* rinit    = (const float*)d_in[11];
  float* out = (float*)d_out;

  const int N  = in_sizes[2];
  const int Hd = in_sizes[3] / in_sizes[5];
  const int L  = in_sizes[5] / Hd;
  const int R  = in_sizes[11] / Hd;
  const int B  = in_sizes[0] / (N * Hd);
  const int T  = N + R;
  const int E  = in_sizes[1] / T;
  const int MW = (E + 63) / 64;
  const float scale = 1.0f / sqrtf((float)Hd);

  char* p = (char*)d_ws;
  auto carve = [&](size_t bytes){ char* r = p; p += (bytes + 255) & ~(size_t)255; return (void*)r; };
  float* h_aug  = (float*)carve((size_t)B*T*Hd*4);
  u16*   proj1b = (u16*)  carve((size_t)B*T*Hd*2);
  u16*   qtb    = (u16*)  carve((size_t)B*T*Hd*2);
  u16*   hyb    = (u16*)  carve((size_t)B*E*Hd*2);
  u16*   hw2t   = (u16*)  carve((size_t)B*Hd*E*2);
  u16*   MqTb   = (u16*)  carve((size_t)L*Hd*Hd*2);
  u16*   W1b    = (u16*)  carve((size_t)L*Hd*Hd*2);
  u16*   W2b    = (u16*)  carve((size_t)L*Hd*Hd*2);
  float* rawb   = (float*)carve((size_t)B*T*4);
  float* vbuf   = (float*)carve((size_t)L*Hd*4);
  u64*   maskw  = (u64*)  carve((size_t)T*MW*8);
  int* counts   = (int*)carve((size_t)R*4);
  int* col_cnt  = (int*)carve((size_t)E*4);
  u16* col_idx  = (u16*)carve((size_t)E*CAPE*2);
  float* mpart  = (float*)carve((size_t)2*B*T*4);
  float* lpart  = (float*)carve((size_t)2*B*T*4);
  float* red2   = (float*)carve((size_t)RF_CH*B*MAXR*Hd*4);

  // scratch: partials (prologue) then Opart (per-layer) — time-disjoint
  size_t used = (size_t)(p - (char*)d_ws);
  size_t rem  = (ws_size > used) ? (ws_size - used) : 0;
  size_t needP  = (size_t)B*NB_RS*R*Hd*4;
  size_t needO2 = (size_t)2*B*T*Hd*2;
  size_t need2 = needP > needO2 ? needP : needO2;
  int SPLIT = (rem >= need2) ? 2 : 1;
  float* partials = (float*)p;
  u16*   Opart    = (u16*)p;

  hipMemsetAsync(counts, 0, (size_t)R*4, stream);

  k_count<<<32, 256, 0, stream>>>(memb, N, counts);

  int total = B*R*Hd;
  int redN;
  if (R <= MAXR){
    k_regsum_fast<<<dim3(NB_RS, B), 128, 0, stream>>>(node_emb, memb, N, R, partials);
    redN = NB_RS;
  } else {
    hipMemsetAsync(partials, 0, (size_t)B*R*Hd*4, stream);
    k_regsum_lds<<<dim3(16, B), Hd, (size_t)R*Hd*4, stream>>>(node_emb, memb, N, R, partials, NB_RS);
    redN = 1;
  }
  k_regfin1b<<<dim3((total+127)/128, RF_CH), 128, 0, stream>>>(partials, NB_RS, redN, R, total, red2);
  k_regfin2<<<(total+255)/256, 256, 0, stream>>>(red2, total, counts, rinit, h_aug, N, R, T, B);

  k_maskbuild<<<T, 256, 0, stream>>>(Hinc, E, MW, maskw);
  k_colbuild2<<<E, 256, 0, stream>>>(maskw, T, MW, col_idx, col_cnt);

  k_ctxv<<<L, Hd, 0, stream>>>(ctx1, W1h, vbuf);
  k_mm128<<<dim3(Hd, L), Hd, 0, stream>>>(W2h, W3, MqTb);
  int wtot = L*Hd*Hd;
  k_wconv<<<(wtot+255)/256, 256, 0, stream>>>(W1, W2, W1b, W2b, wtot);
  k_copyraw<<<dim3(T, B), 128, 0, stream>>>(node_emb, vbuf, h_aug, rawb, N, T, scale);

  int MT = B*T;
  int gTm = (MT + 63)/64;
  int gTf = (T + 63)/64;
  int gEt = (E + 63)/64;
  int ntile = (E + 63)/64;
  int half = (ntile + SPLIT - 1)/SPLIT;
  int swzE = (B == 4 && (E & 1) == 0) ? 1 : 0;
  for (int l = 0; l < L; ++l){
    size_t wo = (size_t)l*Hd*Hd;
    k_gemmM<<<dim3(gTm, 2), 256, 0, stream>>>(h_aug, W1b + wo, MqTb + wo, proj1b, qtb, MT);
    k_edge<<<B*E, 128, 0, stream>>>(swzE, rawb, proj1b, col_cnt, col_idx, hyb, T, E);
    k_gemmW2T<<<dim3(gEt, B), 256, 0, stream>>>(W2b + wo, hyb, hw2t, E);
    k_flashp<<<dim3(gTf, B, SPLIT), 256, 0, stream>>>(qtb, hyb, hw2t, maskw,
                                    Opart, mpart, lpart, T, E, half, scale);
    int writeRaw = (l < L-1) ? 1 : 0;
    const float* vnext = vbuf + (size_t)((l+1 < L) ? (l+1) : l)*Hd;
    k_merge<<<dim3(T, B), 128, 0, stream>>>(Opart, mpart, lpart, SPLIT,
                                    lng + wo/Hd, lnb + wo/Hd,
                                    vnext, rawb, writeRaw,
                                    h_aug, out, T, N, (l == L-1) ? 1 : 0, scale);
  }
}